// Round 1
// baseline (5038.919 us; speedup 1.0000x reference)
//
#include <hip/hip_runtime.h>
#include <math.h>

#define NN 50000
#define NE 500000
// D_IN=128, D_H=256, D_C=768, D_OUT=40

__device__ __forceinline__ float leaky02(float x) { return x > 0.f ? x : 0.2f * x; }

__device__ __forceinline__ void atomicMaxF(float* a, float v) {
    if (v >= 0.f) atomicMax((int*)a, __float_as_int(v));
    else          atomicMin((unsigned int*)a, __float_as_uint(v));
}

// ---------------- generic tiled fp32 GEMM: C = op(preop(A) @ W + bias) ----------------
// A: [Mrows, lda] row-major, W: [K, ldw] row-major, C: [Mrows, ldc] (writes 64-col tile at blockIdx.y*64)
// preop (if scale!=null): a = max(a*scale[k]+shift[k], 0)   (BN + ReLU on A elements)
__global__ __launch_bounds__(256) void mm_gemm64(
    const float* __restrict__ A, int lda,
    const float* __restrict__ W, int ldw,
    const float* __restrict__ bias,
    const float* __restrict__ scale, const float* __restrict__ shift,
    float* __restrict__ C, int ldc,
    int Mrows, int K, int relu_out)
{
    __shared__ float As[64][17];
    __shared__ float Ws[16][64];
    const int tid  = threadIdx.x;
    const int row0 = blockIdx.x * 64;
    const int col0 = blockIdx.y * 64;
    const int ar = tid >> 2, ak = (tid & 3) << 2;   // A staging: 64 rows x 16 k
    const int wk = tid >> 4, wc = (tid & 15) << 2;  // W staging: 16 k x 64 cols
    const int ty = tid >> 4, tx = tid & 15;
    float acc[4][4] = {};

    for (int k0 = 0; k0 < K; k0 += 16) {
        float4 av = make_float4(0.f, 0.f, 0.f, 0.f);
        int grow = row0 + ar;
        if (grow < Mrows) av = *(const float4*)(A + (size_t)grow * lda + k0 + ak);
        if (scale) {
            float4 sc = *(const float4*)(scale + k0 + ak);
            float4 sh = *(const float4*)(shift + k0 + ak);
            av.x = fmaxf(av.x * sc.x + sh.x, 0.f);
            av.y = fmaxf(av.y * sc.y + sh.y, 0.f);
            av.z = fmaxf(av.z * sc.z + sh.z, 0.f);
            av.w = fmaxf(av.w * sc.w + sh.w, 0.f);
        }
        As[ar][ak + 0] = av.x; As[ar][ak + 1] = av.y;
        As[ar][ak + 2] = av.z; As[ar][ak + 3] = av.w;
        *(float4*)(&Ws[wk][wc]) = *(const float4*)(W + (size_t)(k0 + wk) * ldw + col0 + wc);
        __syncthreads();
        #pragma unroll
        for (int kk = 0; kk < 16; ++kk) {
            float b0 = Ws[kk][tx * 4 + 0], b1 = Ws[kk][tx * 4 + 1];
            float b2 = Ws[kk][tx * 4 + 2], b3 = Ws[kk][tx * 4 + 3];
            #pragma unroll
            for (int i = 0; i < 4; ++i) {
                float a = As[ty * 4 + i][kk];
                acc[i][0] += a * b0; acc[i][1] += a * b1;
                acc[i][2] += a * b2; acc[i][3] += a * b3;
            }
        }
        __syncthreads();
    }
    float4 bv = make_float4(0.f, 0.f, 0.f, 0.f);
    if (bias) bv = *(const float4*)(bias + col0 + tx * 4);
    for (int i = 0; i < 4; ++i) {
        int r = row0 + ty * 4 + i;
        if (r < Mrows) {
            float4 o;
            o.x = acc[i][0] + bv.x; o.y = acc[i][1] + bv.y;
            o.z = acc[i][2] + bv.z; o.w = acc[i][3] + bv.w;
            if (relu_out) {
                o.x = fmaxf(o.x, 0.f); o.y = fmaxf(o.y, 0.f);
                o.z = fmaxf(o.z, 0.f); o.w = fmaxf(o.w, 0.f);
            }
            *(float4*)(C + (size_t)r * ldc + col0 + tx * 4) = o;
        }
    }
}

// ---------------- es/ed = xs . att_src / att_dst (one wave per node) ----------------
__global__ __launch_bounds__(256) void mm_dot_attn(const float* __restrict__ xs,
                                                   const float* __restrict__ att_s,
                                                   const float* __restrict__ att_d,
                                                   float* __restrict__ es, float* __restrict__ ed)
{
    int node = blockIdx.x * 4 + (threadIdx.x >> 6);
    int lane = threadIdx.x & 63;
    if (node >= NN) return;
    float4 v = *(const float4*)(xs + (size_t)node * 256 + lane * 4);
    float4 a = *(const float4*)(att_s + lane * 4);
    float4 b = *(const float4*)(att_d + lane * 4);
    float s = v.x * a.x + v.y * a.y + v.z * a.z + v.w * a.w;
    float d = v.x * b.x + v.y * b.y + v.z * b.z + v.w * b.w;
    #pragma unroll
    for (int off = 32; off; off >>= 1) {
        s += __shfl_down(s, off);
        d += __shfl_down(d, off);
    }
    if (lane == 0) { es[node] = s; ed[node] = d; }
}

// node init 1: self-loop attention value seeds max; deg starts at 1 (self loop)
__global__ void mm_gat_init1(const float* __restrict__ es, const float* __restrict__ ed,
                             float* __restrict__ selfv, float* __restrict__ m, int* __restrict__ degc)
{
    int i = blockIdx.x * 256 + threadIdx.x;
    if (i >= NN) return;
    float lv = leaky02(es[i] + ed[i]);
    selfv[i] = lv; m[i] = lv; degc[i] = 1;
}

__global__ void mm_edge_pass1(const int* __restrict__ src, const int* __restrict__ dst,
                              const float* __restrict__ es, const float* __restrict__ ed,
                              float* __restrict__ m, int* __restrict__ degc)
{
    int e = blockIdx.x * 256 + threadIdx.x;
    if (e >= NE) return;
    int s = src[e], d = dst[e];
    float v = leaky02(es[s] + ed[d]);
    atomicMaxF(&m[d], v);
    atomicAdd(&degc[d], 1);
}

// node init 2: denom seeded with self-loop weight; GCN dis = 1/sqrt(deg)
__global__ void mm_gat_init2(const float* __restrict__ selfv, const float* __restrict__ m,
                             const int* __restrict__ degc,
                             float* __restrict__ denom, float* __restrict__ dis)
{
    int i = blockIdx.x * 256 + threadIdx.x;
    if (i >= NN) return;
    denom[i] = expf(selfv[i] - m[i]);
    dis[i] = rsqrtf((float)degc[i]);
}

__global__ void mm_edge_pass2(const int* __restrict__ src, const int* __restrict__ dst,
                              const float* __restrict__ es, const float* __restrict__ ed,
                              const float* __restrict__ m,
                              float* __restrict__ w_e, float* __restrict__ denom)
{
    int e = blockIdx.x * 256 + threadIdx.x;
    if (e >= NE) return;
    int s = src[e], d = dst[e];
    float w = expf(leaky02(es[s] + ed[d]) - m[d]);
    w_e[e] = w;
    unsafeAtomicAdd(&denom[d], w);
}

// GAT self-loop term initializes xc cols [0,256): xc = coef*xs + b_gat
__global__ void mm_gat_self(const float* __restrict__ xs, const float* __restrict__ selfv,
                            const float* __restrict__ m, const float* __restrict__ denom,
                            const float* __restrict__ b_gat, float* __restrict__ xc)
{
    int gid = blockIdx.x * 256 + threadIdx.x;
    int i = gid >> 6, q = gid & 63;
    if (i >= NN) return;
    float coef = expf(selfv[i] - m[i]) / denom[i];
    float4 v = *(const float4*)(xs + (size_t)i * 256 + q * 4);
    float4 b = *(const float4*)(b_gat + q * 4);
    float4 o;
    o.x = coef * v.x + b.x; o.y = coef * v.y + b.y;
    o.z = coef * v.z + b.z; o.w = coef * v.w + b.w;
    *(float4*)(xc + (size_t)i * 768 + q * 4) = o;
}

__global__ void mm_gat_edge(const int* __restrict__ src, const int* __restrict__ dst,
                            const float* __restrict__ xs, const float* __restrict__ w_e,
                            const float* __restrict__ denom, float* __restrict__ xc)
{
    int gid = blockIdx.x * 256 + threadIdx.x;
    int e = gid >> 6, q = gid & 63;
    if (e >= NE) return;
    int s = src[e], d = dst[e];
    float coef = w_e[e] / denom[d];
    float4 v = *(const float4*)(xs + (size_t)s * 256 + q * 4);
    float* o = xc + (size_t)d * 768 + q * 4;
    unsafeAtomicAdd(o + 0, coef * v.x);
    unsafeAtomicAdd(o + 1, coef * v.y);
    unsafeAtomicAdd(o + 2, coef * v.z);
    unsafeAtomicAdd(o + 3, coef * v.w);
}

__global__ void mm_copy_f4(const float* __restrict__ in, float* __restrict__ out, int n4)
{
    int i = blockIdx.x * 256 + threadIdx.x;
    if (i < n4) ((float4*)out)[i] = ((const float4*)in)[i];
}

__global__ void mm_gin_edge(const int* __restrict__ src, const int* __restrict__ dst,
                            const float* __restrict__ x, float* __restrict__ agg)
{
    int gid = blockIdx.x * 256 + threadIdx.x;
    int e = gid >> 5, q = gid & 31;
    if (e >= NE) return;
    int s = src[e], d = dst[e];
    float4 v = *(const float4*)(x + (size_t)s * 128 + q * 4);
    float* o = agg + (size_t)d * 128 + q * 4;
    unsafeAtomicAdd(o + 0, v.x);
    unsafeAtomicAdd(o + 1, v.y);
    unsafeAtomicAdd(o + 2, v.z);
    unsafeAtomicAdd(o + 3, v.w);
}

// GCN self-loop term initializes xc cols [512,768): xc = (1/deg)*xw + b_gcn
__global__ void mm_gcn_self(const float* __restrict__ xw, const float* __restrict__ dis,
                            const float* __restrict__ b_gcn, float* __restrict__ xc)
{
    int gid = blockIdx.x * 256 + threadIdx.x;
    int i = gid >> 6, q = gid & 63;
    if (i >= NN) return;
    float coef = dis[i] * dis[i];
    float4 v = *(const float4*)(xw + (size_t)i * 256 + q * 4);
    float4 b = *(const float4*)(b_gcn + q * 4);
    float4 o;
    o.x = coef * v.x + b.x; o.y = coef * v.y + b.y;
    o.z = coef * v.z + b.z; o.w = coef * v.w + b.w;
    *(float4*)(xc + (size_t)i * 768 + 512 + q * 4) = o;
}

__global__ void mm_gcn_edge(const int* __restrict__ src, const int* __restrict__ dst,
                            const float* __restrict__ xw, const float* __restrict__ dis,
                            float* __restrict__ xc)
{
    int gid = blockIdx.x * 256 + threadIdx.x;
    int e = gid >> 6, q = gid & 63;
    if (e >= NE) return;
    int s = src[e], d = dst[e];
    float coef = dis[s] * dis[d];
    float4 v = *(const float4*)(xw + (size_t)s * 256 + q * 4);
    float* o = xc + (size_t)d * 768 + 512 + q * 4;
    unsafeAtomicAdd(o + 0, coef * v.x);
    unsafeAtomicAdd(o + 1, coef * v.y);
    unsafeAtomicAdd(o + 2, coef * v.z);
    unsafeAtomicAdd(o + 3, coef * v.w);
}

// BN: per-column sum and sum of squares (768 cols), block handles 128 rows
__global__ __launch_bounds__(256) void mm_bn_partial(const float* __restrict__ xc, float* __restrict__ sums)
{
    int r0 = blockIdx.x * 128;
    int rend = min(r0 + 128, NN);
    int c = threadIdx.x;
    float s0 = 0, s1 = 0, s2 = 0, q0 = 0, q1 = 0, q2 = 0;
    for (int r = r0; r < rend; ++r) {
        const float* row = xc + (size_t)r * 768;
        float v0 = row[c], v1 = row[256 + c], v2 = row[512 + c];
        s0 += v0; q0 += v0 * v0;
        s1 += v1; q1 += v1 * v1;
        s2 += v2; q2 += v2 * v2;
    }
    unsafeAtomicAdd(&sums[c], s0);
    unsafeAtomicAdd(&sums[256 + c], s1);
    unsafeAtomicAdd(&sums[512 + c], s2);
    unsafeAtomicAdd(&sums[768 + c], q0);
    unsafeAtomicAdd(&sums[768 + 256 + c], q1);
    unsafeAtomicAdd(&sums[768 + 512 + c], q2);
}

__global__ void mm_bn_fin(const float* __restrict__ sums, const float* __restrict__ gamma,
                          const float* __restrict__ beta,
                          float* __restrict__ scale, float* __restrict__ shift)
{
    int c = blockIdx.x * 256 + threadIdx.x;
    if (c >= 768) return;
    float inv = 1.f / (float)NN;
    float mu = sums[c] * inv;
    float ex2 = sums[768 + c] * inv;
    float var = fmaxf(ex2 - mu * mu, 0.f);
    float rs = rsqrtf(var + 1e-5f);
    float sc = gamma[c] * rs;
    scale[c] = sc;
    shift[c] = beta[c] - mu * sc;
}

// out = h2 @ W2 + b2   (h2: [NN,256], W2: [256,40])
__global__ __launch_bounds__(256) void mm_head2(const float* __restrict__ h2, const float* __restrict__ W2,
                                                const float* __restrict__ b2, float* __restrict__ out)
{
    __shared__ float Ws[256 * 40];
    for (int i = threadIdx.x; i < 256 * 40; i += 256) Ws[i] = W2[i];
    __syncthreads();
    int row = blockIdx.x * 32 + (threadIdx.x >> 3);
    int cg = (threadIdx.x & 7) * 5;
    if (row >= NN) return;
    const float* hr = h2 + (size_t)row * 256;
    float acc[5] = {0, 0, 0, 0, 0};
    for (int k = 0; k < 256; k += 4) {
        float4 a = *(const float4*)(hr + k);
        #pragma unroll
        for (int j = 0; j < 5; ++j) {
            acc[j] += a.x * Ws[(k + 0) * 40 + cg + j] + a.y * Ws[(k + 1) * 40 + cg + j]
                    + a.z * Ws[(k + 2) * 40 + cg + j] + a.w * Ws[(k + 3) * 40 + cg + j];
        }
    }
    #pragma unroll
    for (int j = 0; j < 5; ++j) out[(size_t)row * 40 + cg + j] = acc[j] + b2[cg + j];
}

extern "C" void kernel_launch(void* const* d_in, const int* in_sizes, int n_in,
                              void* d_out, int out_size, void* d_ws, size_t ws_size,
                              hipStream_t stream)
{
    const float* x      = (const float*)d_in[0];
    const int*   ei     = (const int*)d_in[1];
    const float* W_gat  = (const float*)d_in[2];
    const float* att_s  = (const float*)d_in[3];
    const float* att_d  = (const float*)d_in[4];
    const float* b_gat  = (const float*)d_in[5];
    const float* W_gin1 = (const float*)d_in[6];
    const float* b_gin1 = (const float*)d_in[7];
    const float* W_gin2 = (const float*)d_in[8];
    const float* b_gin2 = (const float*)d_in[9];
    const float* W_gcn  = (const float*)d_in[10];
    const float* b_gcn  = (const float*)d_in[11];
    const float* gamma  = (const float*)d_in[12];
    const float* beta   = (const float*)d_in[13];
    const float* W_lin  = (const float*)d_in[14];
    const float* b_lin  = (const float*)d_in[15];
    const float* W_lin2 = (const float*)d_in[16];
    const float* b_lin2 = (const float*)d_in[17];
    const int* src = ei;
    const int* dst = ei + NE;
    float* out = (float*)d_out;

    float* ws = (float*)d_ws;
    size_t off = 0;
    float* xs    = ws + off; off += (size_t)NN * 256;  // GAT xs; later GIN agg (128 cols); later GCN xw
    float* tmpB  = ws + off; off += (size_t)NN * 256;  // GIN hidden; later h2
    float* xc    = ws + off; off += (size_t)NN * 768;  // concat [gat | gin | gcn]
    float* es    = ws + off; off += NN;
    float* ed    = ws + off; off += NN;
    float* selfv = ws + off; off += NN;
    float* mbuf  = ws + off; off += NN;
    float* denom = ws + off; off += NN;
    float* dis   = ws + off; off += NN;
    int*   degc  = (int*)(ws + off); off += NN;
    float* w_e   = ws + off; off += NE;
    float* bnsum = ws + off; off += 1536;
    float* bscale = ws + off; off += 768;
    float* bshift = ws + off; off += 768;

    dim3 blk(256);
    dim3 gemm_grid((NN + 63) / 64, 4);  // 256 output cols

    // ---- GAT ----
    mm_gemm64<<<gemm_grid, blk, 0, stream>>>(x, 128, W_gat, 256, nullptr, nullptr, nullptr,
                                             xs, 256, NN, 128, 0);
    mm_dot_attn<<<(NN + 3) / 4, blk, 0, stream>>>(xs, att_s, att_d, es, ed);
    mm_gat_init1<<<(NN + 255) / 256, blk, 0, stream>>>(es, ed, selfv, mbuf, degc);
    mm_edge_pass1<<<(NE + 255) / 256, blk, 0, stream>>>(src, dst, es, ed, mbuf, degc);
    mm_gat_init2<<<(NN + 255) / 256, blk, 0, stream>>>(selfv, mbuf, degc, denom, dis);
    mm_edge_pass2<<<(NE + 255) / 256, blk, 0, stream>>>(src, dst, es, ed, mbuf, w_e, denom);
    mm_gat_self<<<NN * 64 / 256, blk, 0, stream>>>(xs, selfv, mbuf, denom, b_gat, xc);
    mm_gat_edge<<<NE * 64 / 256, blk, 0, stream>>>(src, dst, xs, w_e, denom, xc);

    // ---- GIN (agg reuses xs buffer, [NN,128]) ----
    mm_copy_f4<<<(NN * 32 + 255) / 256, blk, 0, stream>>>(x, xs, NN * 32);
    mm_gin_edge<<<NE * 32 / 256, blk, 0, stream>>>(src, dst, x, xs);
    mm_gemm64<<<gemm_grid, blk, 0, stream>>>(xs, 128, W_gin1, 256, b_gin1, nullptr, nullptr,
                                             tmpB, 256, NN, 128, 1);
    mm_gemm64<<<gemm_grid, blk, 0, stream>>>(tmpB, 256, W_gin2, 256, b_gin2, nullptr, nullptr,
                                             xc + 256, 768, NN, 256, 0);

    // ---- GCN (xw reuses xs buffer, [NN,256]) ----
    mm_gemm64<<<gemm_grid, blk, 0, stream>>>(x, 128, W_gcn, 256, nullptr, nullptr, nullptr,
                                             xs, 256, NN, 128, 0);
    mm_gcn_self<<<NN * 64 / 256, blk, 0, stream>>>(xs, dis, b_gcn, xc);
    mm_gcn_edge<<<NE * 64 / 256, blk, 0, stream>>>(src, dst, xs, dis, xc);

    // ---- BatchNorm stats ----
    hipMemsetAsync(bnsum, 0, 1536 * sizeof(float), stream);
    mm_bn_partial<<<(NN + 127) / 128, blk, 0, stream>>>(xc, bnsum);
    mm_bn_fin<<<3, blk, 0, stream>>>(bnsum, gamma, beta, bscale, bshift);

    // ---- head: h2 = relu(relu(bn(xc)) @ W_lin + b_lin)  (BN+ReLU fused into A staging) ----
    mm_gemm64<<<gemm_grid, blk, 0, stream>>>(xc, 768, W_lin, 256, b_lin, bscale, bshift,
                                             tmpB, 256, NN, 768, 1);
    // ---- out = h2 @ W_lin2 + b_lin2 ----
    mm_head2<<<(NN + 31) / 32, blk, 0, stream>>>(tmpB, W_lin2, b_lin2, out);
}

// Round 2
// 1387.099 us; speedup vs baseline: 3.6327x; 3.6327x over previous
//
#include <hip/hip_runtime.h>
#include <math.h>

#define NN 50000
#define NE 500000
// D_IN=128, D_H=256, D_C=768, D_OUT=40

__device__ __forceinline__ float leaky02(float x) { return x > 0.f ? x : 0.2f * x; }

// ---------------- generic tiled fp32 GEMM: C = op(preop(A) @ W + bias) ----------------
__global__ __launch_bounds__(256) void mm_gemm64(
    const float* __restrict__ A, int lda,
    const float* __restrict__ W, int ldw,
    const float* __restrict__ bias,
    const float* __restrict__ scale, const float* __restrict__ shift,
    float* __restrict__ C, int ldc,
    int Mrows, int K, int relu_out)
{
    __shared__ float As[64][17];
    __shared__ float Ws[16][64];
    const int tid  = threadIdx.x;
    const int row0 = blockIdx.x * 64;
    const int col0 = blockIdx.y * 64;
    const int ar = tid >> 2, ak = (tid & 3) << 2;
    const int wk = tid >> 4, wc = (tid & 15) << 2;
    const int ty = tid >> 4, tx = tid & 15;
    float acc[4][4] = {};

    for (int k0 = 0; k0 < K; k0 += 16) {
        float4 av = make_float4(0.f, 0.f, 0.f, 0.f);
        int grow = row0 + ar;
        if (grow < Mrows) av = *(const float4*)(A + (size_t)grow * lda + k0 + ak);
        if (scale) {
            float4 sc = *(const float4*)(scale + k0 + ak);
            float4 sh = *(const float4*)(shift + k0 + ak);
            av.x = fmaxf(av.x * sc.x + sh.x, 0.f);
            av.y = fmaxf(av.y * sc.y + sh.y, 0.f);
            av.z = fmaxf(av.z * sc.z + sh.z, 0.f);
            av.w = fmaxf(av.w * sc.w + sh.w, 0.f);
        }
        As[ar][ak + 0] = av.x; As[ar][ak + 1] = av.y;
        As[ar][ak + 2] = av.z; As[ar][ak + 3] = av.w;
        *(float4*)(&Ws[wk][wc]) = *(const float4*)(W + (size_t)(k0 + wk) * ldw + col0 + wc);
        __syncthreads();
        #pragma unroll
        for (int kk = 0; kk < 16; ++kk) {
            float b0 = Ws[kk][tx * 4 + 0], b1 = Ws[kk][tx * 4 + 1];
            float b2 = Ws[kk][tx * 4 + 2], b3 = Ws[kk][tx * 4 + 3];
            #pragma unroll
            for (int i = 0; i < 4; ++i) {
                float a = As[ty * 4 + i][kk];
                acc[i][0] += a * b0; acc[i][1] += a * b1;
                acc[i][2] += a * b2; acc[i][3] += a * b3;
            }
        }
        __syncthreads();
    }
    float4 bv = make_float4(0.f, 0.f, 0.f, 0.f);
    if (bias) bv = *(const float4*)(bias + col0 + tx * 4);
    for (int i = 0; i < 4; ++i) {
        int r = row0 + ty * 4 + i;
        if (r < Mrows) {
            float4 o;
            o.x = acc[i][0] + bv.x; o.y = acc[i][1] + bv.y;
            o.z = acc[i][2] + bv.z; o.w = acc[i][3] + bv.w;
            if (relu_out) {
                o.x = fmaxf(o.x, 0.f); o.y = fmaxf(o.y, 0.f);
                o.z = fmaxf(o.z, 0.f); o.w = fmaxf(o.w, 0.f);
            }
            *(float4*)(C + (size_t)r * ldc + col0 + tx * 4) = o;
        }
    }
}

// ---------------- es/ed = xs . att_src / att_dst (one wave per node) ----------------
__global__ __launch_bounds__(256) void mm_dot_attn(const float* __restrict__ xs,
                                                   const float* __restrict__ att_s,
                                                   const float* __restrict__ att_d,
                                                   float* __restrict__ es, float* __restrict__ ed)
{
    int node = blockIdx.x * 4 + (threadIdx.x >> 6);
    int lane = threadIdx.x & 63;
    if (node >= NN) return;
    float4 v = *(const float4*)(xs + (size_t)node * 256 + lane * 4);
    float4 a = *(const float4*)(att_s + lane * 4);
    float4 b = *(const float4*)(att_d + lane * 4);
    float s = v.x * a.x + v.y * a.y + v.z * a.z + v.w * a.w;
    float d = v.x * b.x + v.y * b.y + v.z * b.z + v.w * b.w;
    #pragma unroll
    for (int off = 32; off; off >>= 1) {
        s += __shfl_down(s, off);
        d += __shfl_down(d, off);
    }
    if (lane == 0) { es[node] = s; ed[node] = d; }
}

// ---------------- CSR build: count -> scan -> fill ----------------
__global__ void mm_count(const int* __restrict__ dst, int* __restrict__ deg)
{
    int e = blockIdx.x * 256 + threadIdx.x;
    if (e >= NE) return;
    atomicAdd(&deg[dst[e]], 1);
}

// single-block exclusive scan; deg and cursor may alias (same-index read-then-write)
__global__ __launch_bounds__(256) void mm_scan(const int* __restrict__ deg,
                                               int* __restrict__ row_ptr, int* __restrict__ cursor)
{
    __shared__ int tile[256];
    __shared__ int carry_s;
    int tid = threadIdx.x;
    if (tid == 0) carry_s = 0;
    __syncthreads();
    for (int base = 0; base < NN; base += 256) {
        int v = (base + tid < NN) ? deg[base + tid] : 0;
        tile[tid] = v;
        __syncthreads();
        #pragma unroll
        for (int off = 1; off < 256; off <<= 1) {
            int a = (tid >= off) ? tile[tid - off] : 0;
            __syncthreads();
            tile[tid] += a;
            __syncthreads();
        }
        int excl = tile[tid] - v;
        int carry = carry_s;
        if (base + tid < NN) {
            row_ptr[base + tid] = carry + excl;
            cursor[base + tid]  = carry + excl;
        }
        __syncthreads();
        if (tid == 255) carry_s = carry + tile[255];
        __syncthreads();
    }
    if (tid == 0) row_ptr[NN] = carry_s;
}

__global__ void mm_fill(const int* __restrict__ src, const int* __restrict__ dst,
                        int* __restrict__ cursor, int* __restrict__ csr_src)
{
    int e = blockIdx.x * 256 + threadIdx.x;
    if (e >= NE) return;
    int pos = atomicAdd(&cursor[dst[e]], 1);
    csr_src[pos] = src[e];
}

__global__ void mm_dis(const int* __restrict__ row_ptr, float* __restrict__ dis)
{
    int i = blockIdx.x * 256 + threadIdx.x;
    if (i >= NN) return;
    dis[i] = rsqrtf((float)(row_ptr[i + 1] - row_ptr[i] + 1));
}

// ---------------- GAT: per-node softmax + weighted aggregation (one block per node) ----------------
__global__ __launch_bounds__(256) void mm_gat_agg(const int* __restrict__ row_ptr, const int* __restrict__ csr_src,
                                                  const float* __restrict__ es, const float* __restrict__ ed,
                                                  const float* __restrict__ xs, const float* __restrict__ b_gat,
                                                  float* __restrict__ xc)
{
    int d = blockIdx.x;
    int tid = threadIdx.x;
    int start = row_ptr[d], end = row_ptr[d + 1];
    float edd = ed[d];
    float selfv = leaky02(es[d] + edd);
    __shared__ float red[256];

    // segment max (self-loop included)
    float lmax = selfv;
    for (int e = start + tid; e < end; e += 256)
        lmax = fmaxf(lmax, leaky02(es[csr_src[e]] + edd));
    red[tid] = lmax; __syncthreads();
    for (int off = 128; off; off >>= 1) {
        if (tid < off) red[tid] = fmaxf(red[tid], red[tid + off]);
        __syncthreads();
    }
    float m = red[0];
    __syncthreads();

    // denominator
    float lsum = (tid == 255) ? __expf(selfv - m) : 0.f;
    for (int e = start + tid; e < end; e += 256)
        lsum += __expf(leaky02(es[csr_src[e]] + edd) - m);
    red[tid] = lsum; __syncthreads();
    for (int off = 128; off; off >>= 1) {
        if (tid < off) red[tid] += red[tid + off];
        __syncthreads();
    }
    float inv_denom = 1.f / red[0];

    // weighted feature gather (thread = channel)
    float acc = __expf(selfv - m) * xs[(size_t)d * 256 + tid];
    for (int e = start; e < end; ++e) {
        int s = csr_src[e];
        float w = __expf(leaky02(es[s] + edd) - m);
        acc += w * xs[(size_t)s * 256 + tid];
    }
    xc[(size_t)d * 768 + tid] = acc * inv_denom + b_gat[tid];
}

// ---------------- GIN: h = x[d] + sum_{s->d} x[s] into xc cols [256,384) ----------------
__global__ __launch_bounds__(256) void mm_gin_agg(const int* __restrict__ row_ptr, const int* __restrict__ csr_src,
                                                  const float* __restrict__ x, float* __restrict__ xc)
{
    int d = blockIdx.x * 2 + (threadIdx.x >> 7);
    int t = threadIdx.x & 127;
    if (d >= NN) return;
    int start = row_ptr[d], end = row_ptr[d + 1];
    float acc = x[(size_t)d * 128 + t];
    for (int e = start; e < end; ++e) {
        int s = csr_src[e];
        acc += x[(size_t)s * 128 + t];
    }
    xc[(size_t)d * 768 + 256 + t] = acc;
}

// ---------------- GCN: symmetric-norm aggregation into xc cols [512,768) ----------------
__global__ __launch_bounds__(256) void mm_gcn_agg(const int* __restrict__ row_ptr, const int* __restrict__ csr_src,
                                                  const float* __restrict__ dis, const float* __restrict__ xw,
                                                  const float* __restrict__ b_gcn, float* __restrict__ xc)
{
    int d = blockIdx.x;
    int t = threadIdx.x;
    int start = row_ptr[d], end = row_ptr[d + 1];
    float disd = dis[d];
    float acc = disd * disd * xw[(size_t)d * 256 + t];
    for (int e = start; e < end; ++e) {
        int s = csr_src[e];
        acc += dis[s] * disd * xw[(size_t)s * 256 + t];
    }
    xc[(size_t)d * 768 + 512 + t] = acc + b_gcn[t];
}

// ---------------- BatchNorm stats ----------------
__global__ __launch_bounds__(256) void mm_bn_partial(const float* __restrict__ xc, float* __restrict__ sums)
{
    int r0 = blockIdx.x * 128;
    int rend = min(r0 + 128, NN);
    int c = threadIdx.x;
    float s0 = 0, s1 = 0, s2 = 0, q0 = 0, q1 = 0, q2 = 0;
    for (int r = r0; r < rend; ++r) {
        const float* row = xc + (size_t)r * 768;
        float v0 = row[c], v1 = row[256 + c], v2 = row[512 + c];
        s0 += v0; q0 += v0 * v0;
        s1 += v1; q1 += v1 * v1;
        s2 += v2; q2 += v2 * v2;
    }
    unsafeAtomicAdd(&sums[c], s0);
    unsafeAtomicAdd(&sums[256 + c], s1);
    unsafeAtomicAdd(&sums[512 + c], s2);
    unsafeAtomicAdd(&sums[768 + c], q0);
    unsafeAtomicAdd(&sums[768 + 256 + c], q1);
    unsafeAtomicAdd(&sums[768 + 512 + c], q2);
}

__global__ void mm_bn_fin(const float* __restrict__ sums, const float* __restrict__ gamma,
                          const float* __restrict__ beta,
                          float* __restrict__ scale, float* __restrict__ shift)
{
    int c = blockIdx.x * 256 + threadIdx.x;
    if (c >= 768) return;
    float inv = 1.f / (float)NN;
    float mu = sums[c] * inv;
    float ex2 = sums[768 + c] * inv;
    float var = fmaxf(ex2 - mu * mu, 0.f);
    float rs = rsqrtf(var + 1e-5f);
    float sc = gamma[c] * rs;
    scale[c] = sc;
    shift[c] = beta[c] - mu * sc;
}

// out = h2 @ W2 + b2   (h2: [NN,256], W2: [256,40])
__global__ __launch_bounds__(256) void mm_head2(const float* __restrict__ h2, const float* __restrict__ W2,
                                                const float* __restrict__ b2, float* __restrict__ out)
{
    __shared__ float Ws[256 * 40];
    for (int i = threadIdx.x; i < 256 * 40; i += 256) Ws[i] = W2[i];
    __syncthreads();
    int row = blockIdx.x * 32 + (threadIdx.x >> 3);
    int cg = (threadIdx.x & 7) * 5;
    if (row >= NN) return;
    const float* hr = h2 + (size_t)row * 256;
    float acc[5] = {0, 0, 0, 0, 0};
    for (int k = 0; k < 256; k += 4) {
        float4 a = *(const float4*)(hr + k);
        #pragma unroll
        for (int j = 0; j < 5; ++j) {
            acc[j] += a.x * Ws[(k + 0) * 40 + cg + j] + a.y * Ws[(k + 1) * 40 + cg + j]
                    + a.z * Ws[(k + 2) * 40 + cg + j] + a.w * Ws[(k + 3) * 40 + cg + j];
        }
    }
    #pragma unroll
    for (int j = 0; j < 5; ++j) out[(size_t)row * 40 + cg + j] = acc[j] + b2[cg + j];
}

extern "C" void kernel_launch(void* const* d_in, const int* in_sizes, int n_in,
                              void* d_out, int out_size, void* d_ws, size_t ws_size,
                              hipStream_t stream)
{
    const float* x      = (const float*)d_in[0];
    const int*   ei     = (const int*)d_in[1];
    const float* W_gat  = (const float*)d_in[2];
    const float* att_s  = (const float*)d_in[3];
    const float* att_d  = (const float*)d_in[4];
    const float* b_gat  = (const float*)d_in[5];
    const float* W_gin1 = (const float*)d_in[6];
    const float* b_gin1 = (const float*)d_in[7];
    const float* W_gin2 = (const float*)d_in[8];
    const float* b_gin2 = (const float*)d_in[9];
    const float* W_gcn  = (const float*)d_in[10];
    const float* b_gcn  = (const float*)d_in[11];
    const float* gamma  = (const float*)d_in[12];
    const float* beta   = (const float*)d_in[13];
    const float* W_lin  = (const float*)d_in[14];
    const float* b_lin  = (const float*)d_in[15];
    const float* W_lin2 = (const float*)d_in[16];
    const float* b_lin2 = (const float*)d_in[17];
    const int* src = ei;
    const int* dst = ei + NE;
    float* out = (float*)d_out;

    float* ws = (float*)d_ws;
    size_t off = 0;
    float* xs     = ws + off; off += (size_t)NN * 256;  // GAT xs; later GCN xw
    float* tmpB   = ws + off; off += (size_t)NN * 256;  // GIN hidden; later h2
    float* xc     = ws + off; off += (size_t)NN * 768;  // concat [gat | gin | gcn]; cols[256,384) stage GIN h
    float* es     = ws + off; off += NN;
    float* ed     = ws + off; off += NN;
    float* dis    = ws + off; off += NN;
    float* bnsum  = ws + off; off += 1536;
    float* bscale = ws + off; off += 768;
    float* bshift = ws + off; off += 768;
    int* row_ptr  = (int*)(ws + off); off += NN + 1;
    int* cursor   = (int*)(ws + off); off += NN;
    int* csr_src  = (int*)(ws + off); off += NE;

    dim3 blk(256);
    dim3 gemm_grid((NN + 63) / 64, 4);  // 256 output cols

    // ---- CSR build (independent of GEMMs) ----
    hipMemsetAsync(cursor, 0, NN * sizeof(int), stream);
    mm_count<<<(NE + 255) / 256, blk, 0, stream>>>(dst, cursor);
    mm_scan<<<1, blk, 0, stream>>>(cursor, row_ptr, cursor);
    mm_dis<<<(NN + 255) / 256, blk, 0, stream>>>(row_ptr, dis);
    mm_fill<<<(NE + 255) / 256, blk, 0, stream>>>(src, dst, cursor, csr_src);

    // ---- GAT ----
    mm_gemm64<<<gemm_grid, blk, 0, stream>>>(x, 128, W_gat, 256, nullptr, nullptr, nullptr,
                                             xs, 256, NN, 128, 0);
    mm_dot_attn<<<(NN + 3) / 4, blk, 0, stream>>>(xs, att_s, att_d, es, ed);
    mm_gat_agg<<<NN, blk, 0, stream>>>(row_ptr, csr_src, es, ed, xs, b_gat, xc);

    // ---- GIN ----
    mm_gin_agg<<<(NN + 1) / 2, blk, 0, stream>>>(row_ptr, csr_src, x, xc);
    mm_gemm64<<<gemm_grid, blk, 0, stream>>>(xc + 256, 768, W_gin1, 256, b_gin1, nullptr, nullptr,
                                             tmpB, 256, NN, 128, 1);
    mm_gemm64<<<gemm_grid, blk, 0, stream>>>(tmpB, 256, W_gin2, 256, b_gin2, nullptr, nullptr,
                                             xc + 256, 768, NN, 256, 0);

    // ---- GCN (xw reuses xs buffer) ----
    mm_gemm64<<<gemm_grid, blk, 0, stream>>>(x, 128, W_gcn, 256, nullptr, nullptr, nullptr,
                                             xs, 256, NN, 128, 0);
    mm_gcn_agg<<<NN, blk, 0, stream>>>(row_ptr, csr_src, dis, xs, b_gcn, xc);

    // ---- BatchNorm stats ----
    hipMemsetAsync(bnsum, 0, 1536 * sizeof(float), stream);
    mm_bn_partial<<<(NN + 127) / 128, blk, 0, stream>>>(xc, bnsum);
    mm_bn_fin<<<3, blk, 0, stream>>>(bnsum, gamma, beta, bscale, bshift);

    // ---- head: h2 = relu(relu(bn(xc)) @ W_lin + b_lin)  (BN+ReLU fused into A staging) ----
    mm_gemm64<<<gemm_grid, blk, 0, stream>>>(xc, 768, W_lin, 256, b_lin, bscale, bshift,
                                             tmpB, 256, NN, 768, 1);
    // ---- out = h2 @ W_lin2 + b_lin2 ----
    mm_head2<<<(NN + 31) / 32, blk, 0, stream>>>(tmpB, W_lin2, b_lin2, out);
}

// Round 3
// 773.104 us; speedup vs baseline: 6.5178x; 1.7942x over previous
//
#include <hip/hip_runtime.h>
#include <math.h>

#define NN 50000
#define NE 500000
// D_IN=128, D_H=256, D_C=768, D_OUT=40

typedef __attribute__((ext_vector_type(8))) short short8;   // 8 bf16 (4 VGPRs)
typedef __attribute__((ext_vector_type(4))) float f32x4;    // MFMA acc

__device__ __forceinline__ float leaky02(float x) { return x > 0.f ? x : 0.2f * x; }
__device__ __forceinline__ ushort f2b(float f) {
    uint u = __float_as_uint(f);
    u += 0x7fffu + ((u >> 16) & 1u);          // RNE
    return (ushort)(u >> 16);
}
__device__ __forceinline__ float b2f(ushort h) { return __uint_as_float(((uint)h) << 16); }
__device__ __forceinline__ float b2f_lo(uint w) { return __uint_as_float(w << 16); }
__device__ __forceinline__ float b2f_hi(uint w) { return __uint_as_float(w & 0xffff0000u); }

// ---------------- fp32 -> bf16 convert (4 elems/thread) ----------------
__global__ void mm_cvt(const float* __restrict__ in, ushort* __restrict__ out, int n)
{
    int i = blockIdx.x * 256 + threadIdx.x;
    if (i * 4 >= n) return;
    float4 v = *(const float4*)(in + (size_t)i * 4);
    uint2 o;
    o.x = (uint)f2b(v.x) | ((uint)f2b(v.y) << 16);
    o.y = (uint)f2b(v.z) | ((uint)f2b(v.w) << 16);
    *(uint2*)(out + (size_t)i * 4) = o;
}

// ---------------- W [K][Nc] fp32 -> Wt [Nc][K] bf16 ----------------
__global__ void mm_wt(const float* __restrict__ W, ushort* __restrict__ Wt, int K, int Nc)
{
    int idx = blockIdx.x * 256 + threadIdx.x;
    if (idx >= K * Nc) return;
    int n = idx / K, k = idx - n * K;
    Wt[idx] = f2b(W[(size_t)k * Nc + n]);
}

// ---------------- bf16 MFMA GEMM: Cb = op(A @ Bt^T + bias), 128x128 tile ----------------
// A: [M][K] bf16 row-major; Bt: [N][K] bf16 row-major (N=256); Cb: [M][ldc] bf16.
__global__ __launch_bounds__(256) void mm_gemm_bf(
    const ushort* __restrict__ A, const ushort* __restrict__ Bt,
    const float* __restrict__ bias,
    ushort* __restrict__ Cb, int ldc,
    int M, int K, int relu)
{
    __shared__ ushort lds[8192];            // As[128][32] | Bs[128][32]
    const int tid = threadIdx.x;
    const int wave = tid >> 6, lane = tid & 63;
    const int row0 = blockIdx.x * 128;
    const int col0 = blockIdx.y * 128;

    // staging addresses: lane covers row (lane>>2), 16B chunk (lane&3); dest = base + lane*16
    int arow0 = min(row0 + wave * 16 + (lane >> 2), M - 1);
    int arow1 = min(row0 + 64 + wave * 16 + (lane >> 2), M - 1);
    int brow0 = col0 + wave * 16 + (lane >> 2);
    int brow1 = col0 + 64 + wave * 16 + (lane >> 2);
    const ushort* pa0 = A + (size_t)arow0 * K + (lane & 3) * 8;
    const ushort* pa1 = A + (size_t)arow1 * K + (lane & 3) * 8;
    const ushort* pb0 = Bt + (size_t)brow0 * K + (lane & 3) * 8;
    const ushort* pb1 = Bt + (size_t)brow1 * K + (lane & 3) * 8;

    ushort* As = lds;
    ushort* Bs = lds + 4096;
    const int wr = (wave >> 1) * 64, wc = (wave & 1) * 64;

    f32x4 zero = {0.f, 0.f, 0.f, 0.f};
    f32x4 acc[4][4];
    #pragma unroll
    for (int m = 0; m < 4; ++m)
        #pragma unroll
        for (int n = 0; n < 4; ++n) acc[m][n] = zero;

    for (int k0 = 0; k0 < K; k0 += 32) {
        __builtin_amdgcn_global_load_lds((const __attribute__((address_space(1))) void*)pa0,
            (__attribute__((address_space(3))) void*)(As + wave * 512), 16, 0, 0);
        __builtin_amdgcn_global_load_lds((const __attribute__((address_space(1))) void*)pa1,
            (__attribute__((address_space(3))) void*)(As + 2048 + wave * 512), 16, 0, 0);
        __builtin_amdgcn_global_load_lds((const __attribute__((address_space(1))) void*)pb0,
            (__attribute__((address_space(3))) void*)(Bs + wave * 512), 16, 0, 0);
        __builtin_amdgcn_global_load_lds((const __attribute__((address_space(1))) void*)pb1,
            (__attribute__((address_space(3))) void*)(Bs + 2048 + wave * 512), 16, 0, 0);
        pa0 += 32; pa1 += 32; pb0 += 32; pb1 += 32;
        __syncthreads();

        short8 a[4], b[4];
        #pragma unroll
        for (int m = 0; m < 4; ++m)
            a[m] = *(const short8*)&As[(wr + m * 16 + (lane & 15)) * 32 + (lane >> 4) * 8];
        #pragma unroll
        for (int n = 0; n < 4; ++n)
            b[n] = *(const short8*)&Bs[(wc + n * 16 + (lane & 15)) * 32 + (lane >> 4) * 8];
        #pragma unroll
        for (int m = 0; m < 4; ++m)
            #pragma unroll
            for (int n = 0; n < 4; ++n)
                acc[m][n] = __builtin_amdgcn_mfma_f32_16x16x32_bf16(a[m], b[n], acc[m][n], 0, 0, 0);
        __syncthreads();
    }

    // epilogue: C/D layout col=lane&15, row=(lane>>4)*4+reg  [m89-verified]
    #pragma unroll
    for (int n = 0; n < 4; ++n) {
        int col = col0 + wc + n * 16 + (lane & 15);
        float bb = bias ? bias[col] : 0.f;
        #pragma unroll
        for (int m = 0; m < 4; ++m) {
            int rb = row0 + wr + m * 16 + (lane >> 4) * 4;
            #pragma unroll
            for (int r = 0; r < 4; ++r) {
                int row = rb + r;
                if (row < M) {
                    float v = acc[m][n][r] + bb;
                    if (relu) v = fmaxf(v, 0.f);
                    Cb[(size_t)row * ldc + col] = f2b(v);
                }
            }
        }
    }
}

// ---------------- es/ed = xs . att_src / att_dst (one wave per node, bf16 xs) ----------------
__global__ __launch_bounds__(256) void mm_dot_attn(const ushort* __restrict__ xsb,
                                                   const float* __restrict__ att_s,
                                                   const float* __restrict__ att_d,
                                                   float* __restrict__ es, float* __restrict__ ed)
{
    int node = blockIdx.x * 4 + (threadIdx.x >> 6);
    int lane = threadIdx.x & 63;
    if (node >= NN) return;
    uint2 w = *(const uint2*)(xsb + (size_t)node * 256 + lane * 4);
    float4 a = *(const float4*)(att_s + lane * 4);
    float4 b = *(const float4*)(att_d + lane * 4);
    float f0 = b2f_lo(w.x), f1 = b2f_hi(w.x), f2 = b2f_lo(w.y), f3 = b2f_hi(w.y);
    float s = f0 * a.x + f1 * a.y + f2 * a.z + f3 * a.w;
    float d = f0 * b.x + f1 * b.y + f2 * b.z + f3 * b.w;
    #pragma unroll
    for (int off = 32; off; off >>= 1) {
        s += __shfl_down(s, off);
        d += __shfl_down(d, off);
    }
    if (lane == 0) { es[node] = s; ed[node] = d; }
}

// ---------------- CSR build: count -> 3-phase scan -> fill ----------------
__global__ void mm_count(const int* __restrict__ dst, int* __restrict__ deg)
{
    int e = blockIdx.x * 256 + threadIdx.x;
    if (e >= NE) return;
    atomicAdd(&deg[dst[e]], 1);
}

__global__ __launch_bounds__(256) void mm_scan1(const int* __restrict__ deg, int* __restrict__ part)
{
    __shared__ int red[256];
    int i = blockIdx.x * 256 + threadIdx.x;
    red[threadIdx.x] = (i < NN) ? deg[i] : 0;
    __syncthreads();
    for (int off = 128; off; off >>= 1) {
        if (threadIdx.x < off) red[threadIdx.x] += red[threadIdx.x + off];
        __syncthreads();
    }
    if (threadIdx.x == 0) part[blockIdx.x] = red[0];
}

__global__ __launch_bounds__(256) void mm_scan2(int* __restrict__ part, int nb)
{
    __shared__ int tile[256];
    int t = threadIdx.x;
    int v = (t < nb) ? part[t] : 0;
    tile[t] = v; __syncthreads();
    for (int off = 1; off < 256; off <<= 1) {
        int a = (t >= off) ? tile[t - off] : 0;
        __syncthreads();
        tile[t] += a;
        __syncthreads();
    }
    if (t < nb) part[t] = tile[t] - v;   // exclusive
}

__global__ __launch_bounds__(256) void mm_scan3(const int* __restrict__ deg, const int* __restrict__ part,
                                                int* __restrict__ row_ptr, int* __restrict__ cursor)
{
    __shared__ int tile[256];
    int t = threadIdx.x;
    int i = blockIdx.x * 256 + t;
    int v = (i < NN) ? deg[i] : 0;
    tile[t] = v; __syncthreads();
    for (int off = 1; off < 256; off <<= 1) {
        int a = (t >= off) ? tile[t - off] : 0;
        __syncthreads();
        tile[t] += a;
        __syncthreads();
    }
    if (i < NN) {
        int ex = part[blockIdx.x] + tile[t] - v;
        row_ptr[i] = ex;
        cursor[i] = ex;
    }
    if (i == 0) row_ptr[NN] = NE;
}

__global__ void mm_fill(const int* __restrict__ src, const int* __restrict__ dst,
                        int* __restrict__ cursor, int* __restrict__ csr_src)
{
    int e = blockIdx.x * 256 + threadIdx.x;
    if (e >= NE) return;
    int pos = atomicAdd(&cursor[dst[e]], 1);
    csr_src[pos] = src[e];
}

__global__ void mm_dis(const int* __restrict__ row_ptr, float* __restrict__ dis)
{
    int i = blockIdx.x * 256 + threadIdx.x;
    if (i >= NN) return;
    dis[i] = rsqrtf((float)(row_ptr[i + 1] - row_ptr[i] + 1));
}

// ---------------- GAT: per-node softmax + weighted aggregation ----------------
__global__ __launch_bounds__(256) void mm_gat_agg(const int* __restrict__ row_ptr, const int* __restrict__ csr_src,
                                                  const float* __restrict__ es, const float* __restrict__ ed,
                                                  const ushort* __restrict__ xsb, const float* __restrict__ b_gat,
                                                  ushort* __restrict__ xcb)
{
    int d = blockIdx.x;
    int tid = threadIdx.x;
    int start = row_ptr[d], end = row_ptr[d + 1];
    float edd = ed[d];
    float selfv = leaky02(es[d] + edd);
    __shared__ float red[256];

    float lmax = selfv;
    for (int e = start + tid; e < end; e += 256)
        lmax = fmaxf(lmax, leaky02(es[csr_src[e]] + edd));
    red[tid] = lmax; __syncthreads();
    for (int off = 128; off; off >>= 1) {
        if (tid < off) red[tid] = fmaxf(red[tid], red[tid + off]);
        __syncthreads();
    }
    float m = red[0];
    __syncthreads();

    float lsum = (tid == 255) ? __expf(selfv - m) : 0.f;
    for (int e = start + tid; e < end; e += 256)
        lsum += __expf(leaky02(es[csr_src[e]] + edd) - m);
    red[tid] = lsum; __syncthreads();
    for (int off = 128; off; off >>= 1) {
        if (tid < off) red[tid] += red[tid + off];
        __syncthreads();
    }
    float inv_denom = 1.f / red[0];

    float acc = __expf(selfv - m) * b2f(xsb[(size_t)d * 256 + tid]);
    for (int e = start; e < end; ++e) {
        int s = csr_src[e];
        float w = __expf(leaky02(es[s] + edd) - m);
        acc += w * b2f(xsb[(size_t)s * 256 + tid]);
    }
    xcb[(size_t)d * 768 + tid] = f2b(acc * inv_denom + b_gat[tid]);
}

// ---------------- GIN: h = x[d] + sum x[s] -> bf16 ----------------
__global__ __launch_bounds__(256) void mm_gin_agg(const int* __restrict__ row_ptr, const int* __restrict__ csr_src,
                                                  const ushort* __restrict__ xb, ushort* __restrict__ gin_hb)
{
    int d = blockIdx.x * 2 + (threadIdx.x >> 7);
    int t = threadIdx.x & 127;
    if (d >= NN) return;
    int start = row_ptr[d], end = row_ptr[d + 1];
    float acc = b2f(xb[(size_t)d * 128 + t]);
    for (int e = start; e < end; ++e)
        acc += b2f(xb[(size_t)csr_src[e] * 128 + t]);
    gin_hb[(size_t)d * 128 + t] = f2b(acc);
}

// ---------------- GCN: symmetric-norm aggregation into xcb cols [512,768) ----------------
__global__ __launch_bounds__(256) void mm_gcn_agg(const int* __restrict__ row_ptr, const int* __restrict__ csr_src,
                                                  const float* __restrict__ dis, const ushort* __restrict__ xwb,
                                                  const float* __restrict__ b_gcn, ushort* __restrict__ xcb)
{
    int d = blockIdx.x;
    int t = threadIdx.x;
    int start = row_ptr[d], end = row_ptr[d + 1];
    float disd = dis[d];
    float acc = disd * disd * b2f(xwb[(size_t)d * 256 + t]);
    for (int e = start; e < end; ++e) {
        int s = csr_src[e];
        acc += dis[s] * disd * b2f(xwb[(size_t)s * 256 + t]);
    }
    xcb[(size_t)d * 768 + 512 + t] = f2b(acc + b_gcn[t]);
}

// ---------------- BatchNorm stats (bf16 input, 2 cols/thread) ----------------
__global__ __launch_bounds__(384) void mm_bn_partial(const ushort* __restrict__ xcb, float* __restrict__ sums)
{
    int r0 = blockIdx.x * 128;
    int rend = min(r0 + 128, NN);
    int t = threadIdx.x;           // cols 2t, 2t+1
    float s0 = 0, q0 = 0, s1 = 0, q1 = 0;
    for (int r = r0; r < rend; ++r) {
        uint w = *(const uint*)(xcb + (size_t)r * 768 + 2 * t);
        float v0 = b2f_lo(w), v1 = b2f_hi(w);
        s0 += v0; q0 += v0 * v0;
        s1 += v1; q1 += v1 * v1;
    }
    unsafeAtomicAdd(&sums[2 * t], s0);
    unsafeAtomicAdd(&sums[2 * t + 1], s1);
    unsafeAtomicAdd(&sums[768 + 2 * t], q0);
    unsafeAtomicAdd(&sums[768 + 2 * t + 1], q1);
}

__global__ void mm_bn_fin(const float* __restrict__ sums, const float* __restrict__ gamma,
                          const float* __restrict__ beta,
                          float* __restrict__ scale, float* __restrict__ shift)
{
    int c = blockIdx.x * 256 + threadIdx.x;
    if (c >= 768) return;
    float inv = 1.f / (float)NN;
    float mu = sums[c] * inv;
    float ex2 = sums[768 + c] * inv;
    float var = fmaxf(ex2 - mu * mu, 0.f);
    float rs = rsqrtf(var + 1e-5f);
    float sc = gamma[c] * rs;
    scale[c] = sc;
    shift[c] = beta[c] - mu * sc;
}

// ---------------- BN+ReLU in place on xcb (8 bf16/thread) ----------------
__global__ void mm_bnrelu(ushort* __restrict__ xcb, const float* __restrict__ sc, const float* __restrict__ sh)
{
    size_t i = (size_t)blockIdx.x * 256 + threadIdx.x;
    if (i >= (size_t)NN * 96) return;
    int c0 = (int)((i % 96) * 8);
    uint4 w = *(const uint4*)(xcb + i * 8);
    float v[8] = {b2f_lo(w.x), b2f_hi(w.x), b2f_lo(w.y), b2f_hi(w.y),
                  b2f_lo(w.z), b2f_hi(w.z), b2f_lo(w.w), b2f_hi(w.w)};
    ushort o[8];
    #pragma unroll
    for (int j = 0; j < 8; ++j)
        o[j] = f2b(fmaxf(v[j] * sc[c0 + j] + sh[c0 + j], 0.f));
    uint4 ow;
    ow.x = (uint)o[0] | ((uint)o[1] << 16);
    ow.y = (uint)o[2] | ((uint)o[3] << 16);
    ow.z = (uint)o[4] | ((uint)o[5] << 16);
    ow.w = (uint)o[6] | ((uint)o[7] << 16);
    *(uint4*)(xcb + i * 8) = ow;
}

// ---------------- out = h2 @ W2 + b2 (h2 bf16 [NN,256], W2 fp32 [256,40]) ----------------
__global__ __launch_bounds__(256) void mm_head2(const ushort* __restrict__ h2b, const float* __restrict__ W2,
                                                const float* __restrict__ b2, float* __restrict__ out)
{
    __shared__ float Ws[256 * 40];
    for (int i = threadIdx.x; i < 256 * 40; i += 256) Ws[i] = W2[i];
    __syncthreads();
    int row = blockIdx.x * 32 + (threadIdx.x >> 3);
    int cg = (threadIdx.x & 7) * 5;
    if (row >= NN) return;
    const ushort* hr = h2b + (size_t)row * 256;
    float acc[5] = {0, 0, 0, 0, 0};
    for (int k = 0; k < 256; k += 8) {
        uint4 w = *(const uint4*)(hr + k);
        float a0 = b2f_lo(w.x), a1 = b2f_hi(w.x), a2 = b2f_lo(w.y), a3 = b2f_hi(w.y);
        float a4 = b2f_lo(w.z), a5 = b2f_hi(w.z), a6 = b2f_lo(w.w), a7 = b2f_hi(w.w);
        #pragma unroll
        for (int j = 0; j < 5; ++j) {
            acc[j] += a0 * Ws[(k + 0) * 40 + cg + j] + a1 * Ws[(k + 1) * 40 + cg + j]
                    + a2 * Ws[(k + 2) * 40 + cg + j] + a3 * Ws[(k + 3) * 40 + cg + j]
                    + a4 * Ws[(k + 4) * 40 + cg + j] + a5 * Ws[(k + 5) * 40 + cg + j]
                    + a6 * Ws[(k + 6) * 40 + cg + j] + a7 * Ws[(k + 7) * 40 + cg + j];
        }
    }
    #pragma unroll
    for (int j = 0; j < 5; ++j) out[(size_t)row * 40 + cg + j] = acc[j] + b2[cg + j];
}

extern "C" void kernel_launch(void* const* d_in, const int* in_sizes, int n_in,
                              void* d_out, int out_size, void* d_ws, size_t ws_size,
                              hipStream_t stream)
{
    const float* x      = (const float*)d_in[0];
    const int*   ei     = (const int*)d_in[1];
    const float* W_gat  = (const float*)d_in[2];
    const float* att_s  = (const float*)d_in[3];
    const float* att_d  = (const float*)d_in[4];
    const float* b_gat  = (const float*)d_in[5];
    const float* W_gin1 = (const float*)d_in[6];
    const float* b_gin1 = (const float*)d_in[7];
    const float* W_gin2 = (const float*)d_in[8];
    const float* b_gin2 = (const float*)d_in[9];
    const float* W_gcn  = (const float*)d_in[10];
    const float* b_gcn  = (const float*)d_in[11];
    const float* gamma  = (const float*)d_in[12];
    const float* beta   = (const float*)d_in[13];
    const float* W_lin  = (const float*)d_in[14];
    const float* b_lin  = (const float*)d_in[15];
    const float* W_lin2 = (const float*)d_in[16];
    const float* b_lin2 = (const float*)d_in[17];
    const int* src = ei;
    const int* dst = ei + NE;
    float* out = (float*)d_out;

    float* ws = (float*)d_ws;
    size_t off = 0;
    ushort* xb      = (ushort*)(ws + off); off += (size_t)NN * 64;    // [NN][128] bf16
    ushort* xsb     = (ushort*)(ws + off); off += (size_t)NN * 128;   // GAT xs; later GCN xw
    ushort* gin_hb  = (ushort*)(ws + off); off += (size_t)NN * 64;    // [NN][128] bf16
    ushort* hid_b   = (ushort*)(ws + off); off += (size_t)NN * 128;   // GIN hidden; later h2
    ushort* xcb     = (ushort*)(ws + off); off += (size_t)NN * 384;   // [NN][768] bf16
    float* es       = ws + off; off += NN;
    float* ed       = ws + off; off += NN;
    float* dis      = ws + off; off += NN;
    float* bnsum    = ws + off; off += 1536;
    float* bscale   = ws + off; off += 768;
    float* bshift   = ws + off; off += 768;
    ushort* wt_gat  = (ushort*)(ws + off); off += 128 * 256 / 2;
    ushort* wt_gin1 = (ushort*)(ws + off); off += 128 * 256 / 2;
    ushort* wt_gin2 = (ushort*)(ws + off); off += 256 * 256 / 2;
    ushort* wt_gcn  = (ushort*)(ws + off); off += 128 * 256 / 2;
    ushort* wt_lin  = (ushort*)(ws + off); off += 768 * 256 / 2;
    int* part       = (int*)(ws + off); off += 256;
    int* row_ptr    = (int*)(ws + off); off += NN + 1;
    int* cursor     = (int*)(ws + off); off += NN;
    int* csr_src    = (int*)(ws + off); off += NE;

    dim3 blk(256);
    dim3 gemm_grid((NN + 127) / 128, 2);   // N=256 -> 2 col blocks
    const int NB = (NN + 255) / 256;       // 196 scan tiles

    // ---- converts / weight transposes ----
    mm_cvt<<<(NN * 128 / 4 + 255) / 256, blk, 0, stream>>>(x, xb, NN * 128);
    mm_wt<<<(128 * 256 + 255) / 256, blk, 0, stream>>>(W_gat, wt_gat, 128, 256);
    mm_wt<<<(128 * 256 + 255) / 256, blk, 0, stream>>>(W_gin1, wt_gin1, 128, 256);
    mm_wt<<<(256 * 256 + 255) / 256, blk, 0, stream>>>(W_gin2, wt_gin2, 256, 256);
    mm_wt<<<(128 * 256 + 255) / 256, blk, 0, stream>>>(W_gcn, wt_gcn, 128, 256);
    mm_wt<<<(768 * 256 + 255) / 256, blk, 0, stream>>>(W_lin, wt_lin, 768, 256);

    // ---- CSR build ----
    hipMemsetAsync(cursor, 0, NN * sizeof(int), stream);
    mm_count<<<(NE + 255) / 256, blk, 0, stream>>>(dst, cursor);
    mm_scan1<<<NB, blk, 0, stream>>>(cursor, part);
    mm_scan2<<<1, blk, 0, stream>>>(part, NB);
    mm_scan3<<<NB, blk, 0, stream>>>(cursor, part, row_ptr, cursor);
    mm_dis<<<(NN + 255) / 256, blk, 0, stream>>>(row_ptr, dis);
    mm_fill<<<(NE + 255) / 256, blk, 0, stream>>>(src, dst, cursor, csr_src);

    // ---- GAT ----
    mm_gemm_bf<<<gemm_grid, blk, 0, stream>>>(xb, wt_gat, nullptr, xsb, 256, NN, 128, 0);
    mm_dot_attn<<<(NN + 3) / 4, blk, 0, stream>>>(xsb, att_s, att_d, es, ed);
    mm_gat_agg<<<NN, blk, 0, stream>>>(row_ptr, csr_src, es, ed, xsb, b_gat, xcb);

    // ---- GIN ----
    mm_gin_agg<<<(NN + 1) / 2, blk, 0, stream>>>(row_ptr, csr_src, xb, gin_hb);
    mm_gemm_bf<<<gemm_grid, blk, 0, stream>>>(gin_hb, wt_gin1, b_gin1, hid_b, 256, NN, 128, 1);
    mm_gemm_bf<<<gemm_grid, blk, 0, stream>>>(hid_b, wt_gin2, b_gin2, xcb + 256, 768, NN, 256, 0);

    // ---- GCN (xwb reuses xsb; GAT consumers already done) ----
    mm_gemm_bf<<<gemm_grid, blk, 0, stream>>>(xb, wt_gcn, nullptr, xsb, 256, NN, 128, 0);
    mm_gcn_agg<<<NN, blk, 0, stream>>>(row_ptr, csr_src, dis, xsb, b_gcn, xcb);

    // ---- BatchNorm ----
    hipMemsetAsync(bnsum, 0, 1536 * sizeof(float), stream);
    mm_bn_partial<<<(NN + 127) / 128, dim3(384), 0, stream>>>(xcb, bnsum);
    mm_bn_fin<<<3, blk, 0, stream>>>(bnsum, gamma, beta, bscale, bshift);
    mm_bnrelu<<<(int)(((size_t)NN * 96 + 255) / 256), blk, 0, stream>>>(xcb, bscale, bshift);

    // ---- head ----
    mm_gemm_bf<<<gemm_grid, blk, 0, stream>>>(xcb, wt_lin, b_lin, hid_b, 256, NN, 768, 1);
    mm_head2<<<(NN + 31) / 32, blk, 0, stream>>>(hid_b, W_lin2, b_lin2, out);
}

// Round 4
// 496.187 us; speedup vs baseline: 10.1553x; 1.5581x over previous
//
#include <hip/hip_runtime.h>
#include <math.h>

#define NN 50000
#define NE 500000
// D_IN=128, D_H=256, D_C=768, D_OUT=40

typedef __attribute__((ext_vector_type(8))) short short8;   // 8 bf16 (4 VGPRs)
typedef __attribute__((ext_vector_type(4))) float f32x4;    // MFMA acc

__device__ __forceinline__ float leaky02(float x) { return x > 0.f ? x : 0.2f * x; }
__device__ __forceinline__ ushort f2b(float f) {
    uint u = __float_as_uint(f);
    u += 0x7fffu + ((u >> 16) & 1u);          // RNE
    return (ushort)(u >> 16);
}
__device__ __forceinline__ float b2f(ushort h) { return __uint_as_float(((uint)h) << 16); }
__device__ __forceinline__ float b2f_lo(uint w) { return __uint_as_float(w << 16); }
__device__ __forceinline__ float b2f_hi(uint w) { return __uint_as_float(w & 0xffff0000u); }

// ---------------- fp32 -> bf16 convert (4 elems/thread) ----------------
__global__ void mm_cvt(const float* __restrict__ in, ushort* __restrict__ out, int n)
{
    int i = blockIdx.x * 256 + threadIdx.x;
    if (i * 4 >= n) return;
    float4 v = *(const float4*)(in + (size_t)i * 4);
    uint2 o;
    o.x = (uint)f2b(v.x) | ((uint)f2b(v.y) << 16);
    o.y = (uint)f2b(v.z) | ((uint)f2b(v.w) << 16);
    *(uint2*)(out + (size_t)i * 4) = o;
}

// ---------------- W [K][Nc] fp32 -> Wt [Nc][K] bf16 ----------------
__global__ void mm_wt(const float* __restrict__ W, ushort* __restrict__ Wt, int K, int Nc)
{
    int idx = blockIdx.x * 256 + threadIdx.x;
    if (idx >= K * Nc) return;
    int n = idx / K, k = idx - n * K;
    Wt[idx] = f2b(W[(size_t)k * Nc + n]);
}

// ---------------- va = W_gat @ att_src, vd = W_gat @ att_dst (both [128]) ----------------
__global__ void mm_attvec(const float* __restrict__ W, const float* __restrict__ as_,
                          const float* __restrict__ ad_, float* __restrict__ va, float* __restrict__ vd)
{
    int i = threadIdx.x;           // 0..255
    const float* vec = (i < 128) ? as_ : ad_;
    int k = i & 127;
    float s = 0.f;
    for (int j = 0; j < 256; ++j) s += W[(size_t)k * 256 + j] * vec[j];
    if (i < 128) va[k] = s; else vd[k] = s;
}

// ---------------- es/ed = x . va / vd (one wave per node, fp32 x) ----------------
__global__ __launch_bounds__(256) void mm_esed(const float* __restrict__ x,
                                               const float* __restrict__ va, const float* __restrict__ vd,
                                               float* __restrict__ es, float* __restrict__ ed)
{
    int node = blockIdx.x * 4 + (threadIdx.x >> 6);
    int lane = threadIdx.x & 63;
    if (node >= NN) return;
    float2 xv = *(const float2*)(x + (size_t)node * 128 + lane * 2);
    float2 a = *(const float2*)(va + lane * 2);
    float2 b = *(const float2*)(vd + lane * 2);
    float s = xv.x * a.x + xv.y * a.y;
    float d = xv.x * b.x + xv.y * b.y;
    #pragma unroll
    for (int off = 32; off; off >>= 1) {
        s += __shfl_down(s, off);
        d += __shfl_down(d, off);
    }
    if (lane == 0) { es[node] = s; ed[node] = d; }
}

// ---------------- CSR build: count -> 3-phase scan -> fill ----------------
__global__ void mm_count(const int* __restrict__ dst, int* __restrict__ deg)
{
    int e = blockIdx.x * 256 + threadIdx.x;
    if (e >= NE) return;
    atomicAdd(&deg[dst[e]], 1);
}

__global__ __launch_bounds__(256) void mm_scan1(const int* __restrict__ deg, int* __restrict__ part)
{
    __shared__ int red[256];
    int i = blockIdx.x * 256 + threadIdx.x;
    red[threadIdx.x] = (i < NN) ? deg[i] : 0;
    __syncthreads();
    for (int off = 128; off; off >>= 1) {
        if (threadIdx.x < off) red[threadIdx.x] += red[threadIdx.x + off];
        __syncthreads();
    }
    if (threadIdx.x == 0) part[blockIdx.x] = red[0];
}

__global__ __launch_bounds__(256) void mm_scan2(int* __restrict__ part, int nb)
{
    __shared__ int tile[256];
    int t = threadIdx.x;
    int v = (t < nb) ? part[t] : 0;
    tile[t] = v; __syncthreads();
    for (int off = 1; off < 256; off <<= 1) {
        int a = (t >= off) ? tile[t - off] : 0;
        __syncthreads();
        tile[t] += a;
        __syncthreads();
    }
    if (t < nb) part[t] = tile[t] - v;   // exclusive
}

__global__ __launch_bounds__(256) void mm_scan3(const int* __restrict__ deg, const int* __restrict__ part,
                                                int* __restrict__ row_ptr, int* __restrict__ cursor)
{
    __shared__ int tile[256];
    int t = threadIdx.x;
    int i = blockIdx.x * 256 + t;
    int v = (i < NN) ? deg[i] : 0;
    tile[t] = v; __syncthreads();
    for (int off = 1; off < 256; off <<= 1) {
        int a = (t >= off) ? tile[t - off] : 0;
        __syncthreads();
        tile[t] += a;
        __syncthreads();
    }
    if (i < NN) {
        int ex = part[blockIdx.x] + tile[t] - v;
        row_ptr[i] = ex;
        cursor[i] = ex;
    }
    if (i == 0) row_ptr[NN] = NE;
}

__global__ void mm_fill(const int* __restrict__ src, const int* __restrict__ dst,
                        int* __restrict__ cursor, int* __restrict__ csr_src)
{
    int e = blockIdx.x * 256 + threadIdx.x;
    if (e >= NE) return;
    int pos = atomicAdd(&cursor[dst[e]], 1);
    csr_src[pos] = src[e];
}

__global__ void mm_dis(const int* __restrict__ row_ptr, float* __restrict__ dis)
{
    int i = blockIdx.x * 256 + threadIdx.x;
    if (i >= NN) return;
    dis[i] = rsqrtf((float)(row_ptr[i + 1] - row_ptr[i] + 1));
}

// ---------------- per-edge alpha (GAT softmax) + GCN norm, one wave per node ----------------
__global__ __launch_bounds__(256) void mm_alpha(const int* __restrict__ row_ptr, const int* __restrict__ csr_src,
                                                const float* __restrict__ es, const float* __restrict__ ed,
                                                const float* __restrict__ dis,
                                                float* __restrict__ alpha, float* __restrict__ normw,
                                                float* __restrict__ alpha_self)
{
    int d = blockIdx.x * 4 + (threadIdx.x >> 6);
    int lane = threadIdx.x & 63;
    if (d >= NN) return;
    int start = row_ptr[d], end = row_ptr[d + 1];
    float edd = ed[d], disd = dis[d];
    float selfv = leaky02(es[d] + edd);

    float lmax = selfv;
    for (int e = start + lane; e < end; e += 64)
        lmax = fmaxf(lmax, leaky02(es[csr_src[e]] + edd));
    #pragma unroll
    for (int off = 32; off; off >>= 1) lmax = fmaxf(lmax, __shfl_xor(lmax, off));
    float m = lmax;

    float lsum = (lane == 0) ? __expf(selfv - m) : 0.f;
    for (int e = start + lane; e < end; e += 64)
        lsum += __expf(leaky02(es[csr_src[e]] + edd) - m);
    #pragma unroll
    for (int off = 32; off; off >>= 1) lsum += __shfl_xor(lsum, off);
    float inv = 1.f / lsum;

    for (int e = start + lane; e < end; e += 64) {
        int s = csr_src[e];
        alpha[e] = __expf(leaky02(es[s] + edd) - m) * inv;
        normw[e] = dis[s] * disd;
    }
    if (lane == 0) alpha_self[d] = __expf(selfv - m) * inv;
}

// ---------------- fused gather: 3 weighted sums over x rows (128 ch), 4 edge-groups x 64 lanes ----------------
// out aggb[d][0:128]=GAT, [128:256]=GIN(+self), [256:384]=GCN
__global__ __launch_bounds__(256) void mm_gather3(const int* __restrict__ row_ptr, const int* __restrict__ csr_src,
                                                  const float* __restrict__ alpha, const float* __restrict__ normw,
                                                  const float* __restrict__ alpha_self, const float* __restrict__ dis,
                                                  const ushort* __restrict__ xb, ushort* __restrict__ aggb)
{
    int d = blockIdx.x;
    int tid = threadIdx.x, grp = tid >> 6, lane = tid & 63;
    int start = row_ptr[d], end = row_ptr[d + 1];
    float gat0 = 0, gat1 = 0, gin0 = 0, gin1 = 0, gcn0 = 0, gcn1 = 0;
    if (grp == 0) {
        uint w = *(const uint*)(xb + (size_t)d * 128 + lane * 2);
        float x0 = b2f_lo(w), x1 = b2f_hi(w);
        float as_ = alpha_self[d];
        float dd = dis[d], d2 = dd * dd;
        gat0 = as_ * x0; gat1 = as_ * x1;
        gin0 = x0;       gin1 = x1;
        gcn0 = d2 * x0;  gcn1 = d2 * x1;
    }
    for (int e = start + grp; e < end; e += 4) {
        int s = csr_src[e];
        float al = alpha[e], nw = normw[e];
        uint w = *(const uint*)(xb + (size_t)s * 128 + lane * 2);
        float x0 = b2f_lo(w), x1 = b2f_hi(w);
        gat0 += al * x0; gat1 += al * x1;
        gin0 += x0;      gin1 += x1;
        gcn0 += nw * x0; gcn1 += nw * x1;
    }
    __shared__ float red[4][384];
    red[grp][lane * 2]           = gat0; red[grp][lane * 2 + 1]       = gat1;
    red[grp][128 + lane * 2]     = gin0; red[grp][128 + lane * 2 + 1] = gin1;
    red[grp][256 + lane * 2]     = gcn0; red[grp][256 + lane * 2 + 1] = gcn1;
    __syncthreads();
    ushort* orow = aggb + (size_t)d * 384;
    for (int v = tid; v < 384; v += 256) {
        float s = red[0][v] + red[1][v] + red[2][v] + red[3][v];
        orow[v] = f2b(s);
    }
}

// ---------------- bf16 MFMA GEMM: Cb = op(A @ Bt^T + bias), 128x128 tile ----------------
// A: [M][lda] bf16 row-major (uses K cols); Bt: [N][K] bf16; Cb: [M][ldc] bf16.
__global__ __launch_bounds__(256) void mm_gemm_bf(
    const ushort* __restrict__ A, int lda, const ushort* __restrict__ Bt,
    const float* __restrict__ bias,
    ushort* __restrict__ Cb, int ldc,
    int M, int K, int relu)
{
    __shared__ ushort lds[8192];            // As[128][32] | Bs[128][32]
    const int tid = threadIdx.x;
    const int wave = tid >> 6, lane = tid & 63;
    const int row0 = blockIdx.x * 128;
    const int col0 = blockIdx.y * 128;

    int arow0 = min(row0 + wave * 16 + (lane >> 2), M - 1);
    int arow1 = min(row0 + 64 + wave * 16 + (lane >> 2), M - 1);
    int brow0 = col0 + wave * 16 + (lane >> 2);
    int brow1 = col0 + 64 + wave * 16 + (lane >> 2);
    const ushort* pa0 = A + (size_t)arow0 * lda + (lane & 3) * 8;
    const ushort* pa1 = A + (size_t)arow1 * lda + (lane & 3) * 8;
    const ushort* pb0 = Bt + (size_t)brow0 * K + (lane & 3) * 8;
    const ushort* pb1 = Bt + (size_t)brow1 * K + (lane & 3) * 8;

    ushort* As = lds;
    ushort* Bs = lds + 4096;
    const int wr = (wave >> 1) * 64, wc = (wave & 1) * 64;

    f32x4 zero = {0.f, 0.f, 0.f, 0.f};
    f32x4 acc[4][4];
    #pragma unroll
    for (int m = 0; m < 4; ++m)
        #pragma unroll
        for (int n = 0; n < 4; ++n) acc[m][n] = zero;

    for (int k0 = 0; k0 < K; k0 += 32) {
        __builtin_amdgcn_global_load_lds((const __attribute__((address_space(1))) void*)pa0,
            (__attribute__((address_space(3))) void*)(As + wave * 512), 16, 0, 0);
        __builtin_amdgcn_global_load_lds((const __attribute__((address_space(1))) void*)pa1,
            (__attribute__((address_space(3))) void*)(As + 2048 + wave * 512), 16, 0, 0);
        __builtin_amdgcn_global_load_lds((const __attribute__((address_space(1))) void*)pb0,
            (__attribute__((address_space(3))) void*)(Bs + wave * 512), 16, 0, 0);
        __builtin_amdgcn_global_load_lds((const __attribute__((address_space(1))) void*)pb1,
            (__attribute__((address_space(3))) void*)(Bs + 2048 + wave * 512), 16, 0, 0);
        pa0 += 32; pa1 += 32; pb0 += 32; pb1 += 32;
        __syncthreads();

        short8 a[4], b[4];
        #pragma unroll
        for (int m = 0; m < 4; ++m)
            a[m] = *(const short8*)&As[(wr + m * 16 + (lane & 15)) * 32 + (lane >> 4) * 8];
        #pragma unroll
        for (int n = 0; n < 4; ++n)
            b[n] = *(const short8*)&Bs[(wc + n * 16 + (lane & 15)) * 32 + (lane >> 4) * 8];
        #pragma unroll
        for (int m = 0; m < 4; ++m)
            #pragma unroll
            for (int n = 0; n < 4; ++n)
                acc[m][n] = __builtin_amdgcn_mfma_f32_16x16x32_bf16(a[m], b[n], acc[m][n], 0, 0, 0);
        __syncthreads();
    }

    // epilogue: C/D layout col=lane&15, row=(lane>>4)*4+reg  [m89-verified]
    #pragma unroll
    for (int n = 0; n < 4; ++n) {
        int col = col0 + wc + n * 16 + (lane & 15);
        float bb = bias ? bias[col] : 0.f;
        #pragma unroll
        for (int m = 0; m < 4; ++m) {
            int rb = row0 + wr + m * 16 + (lane >> 4) * 4;
            #pragma unroll
            for (int r = 0; r < 4; ++r) {
                int row = rb + r;
                if (row < M) {
                    float v = acc[m][n][r] + bb;
                    if (relu) v = fmaxf(v, 0.f);
                    Cb[(size_t)row * ldc + col] = f2b(v);
                }
            }
        }
    }
}

// ---------------- BatchNorm stats (bf16 input, 2 cols/thread) ----------------
__global__ __launch_bounds__(384) void mm_bn_partial(const ushort* __restrict__ xcb, float* __restrict__ sums)
{
    int r0 = blockIdx.x * 128;
    int rend = min(r0 + 128, NN);
    int t = threadIdx.x;           // cols 2t, 2t+1
    float s0 = 0, q0 = 0, s1 = 0, q1 = 0;
    for (int r = r0; r < rend; ++r) {
        uint w = *(const uint*)(xcb + (size_t)r * 768 + 2 * t);
        float v0 = b2f_lo(w), v1 = b2f_hi(w);
        s0 += v0; q0 += v0 * v0;
        s1 += v1; q1 += v1 * v1;
    }
    unsafeAtomicAdd(&sums[2 * t], s0);
    unsafeAtomicAdd(&sums[2 * t + 1], s1);
    unsafeAtomicAdd(&sums[768 + 2 * t], q0);
    unsafeAtomicAdd(&sums[768 + 2 * t + 1], q1);
}

__global__ void mm_bn_fin(const float* __restrict__ sums, const float* __restrict__ gamma,
                          const float* __restrict__ beta,
                          float* __restrict__ scale, float* __restrict__ shift)
{
    int c = blockIdx.x * 256 + threadIdx.x;
    if (c >= 768) return;
    float inv = 1.f / (float)NN;
    float mu = sums[c] * inv;
    float ex2 = sums[768 + c] * inv;
    float var = fmaxf(ex2 - mu * mu, 0.f);
    float rs = rsqrtf(var + 1e-5f);
    float sc = gamma[c] * rs;
    scale[c] = sc;
    shift[c] = beta[c] - mu * sc;
}

// ---------------- BN+ReLU in place on xcb (8 bf16/thread) ----------------
__global__ void mm_bnrelu(ushort* __restrict__ xcb, const float* __restrict__ sc, const float* __restrict__ sh)
{
    size_t i = (size_t)blockIdx.x * 256 + threadIdx.x;
    if (i >= (size_t)NN * 96) return;
    int c0 = (int)((i % 96) * 8);
    uint4 w = *(const uint4*)(xcb + i * 8);
    float v[8] = {b2f_lo(w.x), b2f_hi(w.x), b2f_lo(w.y), b2f_hi(w.y),
                  b2f_lo(w.z), b2f_hi(w.z), b2f_lo(w.w), b2f_hi(w.w)};
    ushort o[8];
    #pragma unroll
    for (int j = 0; j < 8; ++j)
        o[j] = f2b(fmaxf(v[j] * sc[c0 + j] + sh[c0 + j], 0.f));
    uint4 ow;
    ow.x = (uint)o[0] | ((uint)o[1] << 16);
    ow.y = (uint)o[2] | ((uint)o[3] << 16);
    ow.z = (uint)o[4] | ((uint)o[5] << 16);
    ow.w = (uint)o[6] | ((uint)o[7] << 16);
    *(uint4*)(xcb + i * 8) = ow;
}

// ---------------- out = h2 @ W2 + b2 (h2 bf16 [NN,256], W2 fp32 [256,40]) ----------------
__global__ __launch_bounds__(256) void mm_head2(const ushort* __restrict__ h2b, const float* __restrict__ W2,
                                                const float* __restrict__ b2, float* __restrict__ out)
{
    __shared__ float Ws[256 * 40];
    for (int i = threadIdx.x; i < 256 * 40; i += 256) Ws[i] = W2[i];
    __syncthreads();
    int row = blockIdx.x * 32 + (threadIdx.x >> 3);
    int cg = (threadIdx.x & 7) * 5;
    if (row >= NN) return;
    const ushort* hr = h2b + (size_t)row * 256;
    float acc[5] = {0, 0, 0, 0, 0};
    for (int k = 0; k < 256; k += 8) {
        uint4 w = *(const uint4*)(hr + k);
        float a0 = b2f_lo(w.x), a1 = b2f_hi(w.x), a2 = b2f_lo(w.y), a3 = b2f_hi(w.y);
        float a4 = b2f_lo(w.z), a5 = b2f_hi(w.z), a6 = b2f_lo(w.w), a7 = b2f_hi(w.w);
        #pragma unroll
        for (int j = 0; j < 5; ++j) {
            acc[j] += a0 * Ws[(k + 0) * 40 + cg + j] + a1 * Ws[(k + 1) * 40 + cg + j]
                    + a2 * Ws[(k + 2) * 40 + cg + j] + a3 * Ws[(k + 3) * 40 + cg + j]
                    + a4 * Ws[(k + 4) * 40 + cg + j] + a5 * Ws[(k + 5) * 40 + cg + j]
                    + a6 * Ws[(k + 6) * 40 + cg + j] + a7 * Ws[(k + 7) * 40 + cg + j];
        }
    }
    #pragma unroll
    for (int j = 0; j < 5; ++j) out[(size_t)row * 40 + cg + j] = acc[j] + b2[cg + j];
}

extern "C" void kernel_launch(void* const* d_in, const int* in_sizes, int n_in,
                              void* d_out, int out_size, void* d_ws, size_t ws_size,
                              hipStream_t stream)
{
    const float* x      = (const float*)d_in[0];
    const int*   ei     = (const int*)d_in[1];
    const float* W_gat  = (const float*)d_in[2];
    const float* att_s  = (const float*)d_in[3];
    const float* att_d  = (const float*)d_in[4];
    const float* b_gat  = (const float*)d_in[5];
    const float* W_gin1 = (const float*)d_in[6];
    const float* b_gin1 = (const float*)d_in[7];
    const float* W_gin2 = (const float*)d_in[8];
    const float* b_gin2 = (const float*)d_in[9];
    const float* W_gcn  = (const float*)d_in[10];
    const float* b_gcn  = (const float*)d_in[11];
    const float* gamma  = (const float*)d_in[12];
    const float* beta   = (const float*)d_in[13];
    const float* W_lin  = (const float*)d_in[14];
    const float* b_lin  = (const float*)d_in[15];
    const float* W_lin2 = (const float*)d_in[16];
    const float* b_lin2 = (const float*)d_in[17];
    const int* src = ei;
    const int* dst = ei + NE;
    float* out = (float*)d_out;

    float* ws = (float*)d_ws;
    size_t off = 0;
    ushort* xb      = (ushort*)(ws + off); off += (size_t)NN * 64;    // [NN][128] bf16
    ushort* aggb    = (ushort*)(ws + off); off += (size_t)NN * 192;   // [NN][384] bf16: gat|gin|gcn
    ushort* hid_b   = (ushort*)(ws + off); off += (size_t)NN * 128;   // GIN hidden; later h2
    ushort* xcb     = (ushort*)(ws + off); off += (size_t)NN * 384;   // [NN][768] bf16
    float* es       = ws + off; off += NN;
    float* ed       = ws + off; off += NN;
    float* dis      = ws + off; off += NN;
    float* alpha    = ws + off; off += NE;
    float* normw    = ws + off; off += NE;
    float* aself    = ws + off; off += NN;
    float* va       = ws + off; off += 128;
    float* vd       = ws + off; off += 128;
    float* bnsum    = ws + off; off += 1536;
    float* bscale   = ws + off; off += 768;
    float* bshift   = ws + off; off += 768;
    ushort* wt_gat  = (ushort*)(ws + off); off += 128 * 256 / 2;
    ushort* wt_gin1 = (ushort*)(ws + off); off += 128 * 256 / 2;
    ushort* wt_gin2 = (ushort*)(ws + off); off += 256 * 256 / 2;
    ushort* wt_gcn  = (ushort*)(ws + off); off += 128 * 256 / 2;
    ushort* wt_lin  = (ushort*)(ws + off); off += 768 * 256 / 2;
    int* part       = (int*)(ws + off); off += 256;
    int* row_ptr    = (int*)(ws + off); off += NN + 1;
    int* cursor     = (int*)(ws + off); off += NN;
    int* csr_src    = (int*)(ws + off); off += NE;

    dim3 blk(256);
    dim3 gemm_grid((NN + 127) / 128, 2);   // N=256 -> 2 col blocks
    const int NB = (NN + 255) / 256;       // scan tiles

    // ---- converts / weight transposes / attention vectors ----
    mm_cvt<<<(NN * 128 / 4 + 255) / 256, blk, 0, stream>>>(x, xb, NN * 128);
    mm_wt<<<(128 * 256 + 255) / 256, blk, 0, stream>>>(W_gat, wt_gat, 128, 256);
    mm_wt<<<(128 * 256 + 255) / 256, blk, 0, stream>>>(W_gin1, wt_gin1, 128, 256);
    mm_wt<<<(256 * 256 + 255) / 256, blk, 0, stream>>>(W_gin2, wt_gin2, 256, 256);
    mm_wt<<<(128 * 256 + 255) / 256, blk, 0, stream>>>(W_gcn, wt_gcn, 128, 256);
    mm_wt<<<(768 * 256 + 255) / 256, blk, 0, stream>>>(W_lin, wt_lin, 768, 256);
    mm_attvec<<<1, blk, 0, stream>>>(W_gat, att_s, att_d, va, vd);

    // ---- CSR build ----
    hipMemsetAsync(cursor, 0, NN * sizeof(int), stream);
    mm_count<<<(NE + 255) / 256, blk, 0, stream>>>(dst, cursor);
    mm_scan1<<<NB, blk, 0, stream>>>(cursor, part);
    mm_scan2<<<1, blk, 0, stream>>>(part, NB);
    mm_scan3<<<NB, blk, 0, stream>>>(cursor, part, row_ptr, cursor);
    mm_dis<<<(NN + 255) / 256, blk, 0, stream>>>(row_ptr, dis);
    mm_fill<<<(NE + 255) / 256, blk, 0, stream>>>(src, dst, cursor, csr_src);

    // ---- attention scores + per-edge weights ----
    mm_esed<<<(NN + 3) / 4, blk, 0, stream>>>(x, va, vd, es, ed);
    mm_alpha<<<(NN + 3) / 4, blk, 0, stream>>>(row_ptr, csr_src, es, ed, dis, alpha, normw, aself);

    // ---- fused gather over x (128 ch): GAT | GIN | GCN ----
    mm_gather3<<<NN, blk, 0, stream>>>(row_ptr, csr_src, alpha, normw, aself, dis, xb, aggb);

    // ---- GEMMs ----
    mm_gemm_bf<<<gemm_grid, blk, 0, stream>>>(aggb,       384, wt_gat,  b_gat,  xcb,       768, NN, 128, 0);
    mm_gemm_bf<<<gemm_grid, blk, 0, stream>>>(aggb + 128, 384, wt_gin1, b_gin1, hid_b,     256, NN, 128, 1);
    mm_gemm_bf<<<gemm_grid, blk, 0, stream>>>(hid_b,      256, wt_gin2, b_gin2, xcb + 256, 768, NN, 256, 0);
    mm_gemm_bf<<<gemm_grid, blk, 0, stream>>>(aggb + 256, 384, wt_gcn,  b_gcn,  xcb + 512, 768, NN, 128, 0);

    // ---- BatchNorm ----
    hipMemsetAsync(bnsum, 0, 1536 * sizeof(float), stream);
    mm_bn_partial<<<(NN + 127) / 128, dim3(384), 0, stream>>>(xcb, bnsum);
    mm_bn_fin<<<3, blk, 0, stream>>>(bnsum, gamma, beta, bscale, bshift);
    mm_bnrelu<<<(int)(((size_t)NN * 96 + 255) / 256), blk, 0, stream>>>(xcb, bscale, bshift);

    // ---- head ----
    mm_gemm_bf<<<gemm_grid, blk, 0, stream>>>(xcb, 768, wt_lin, b_lin, hid_b, 256, NN, 768, 1);
    mm_head2<<<(NN + 31) / 32, blk, 0, stream>>>(hid_b, W_lin2, b_lin2, out);
}

// Round 5
// 430.800 us; speedup vs baseline: 11.6966x; 1.1518x over previous
//
#include <hip/hip_runtime.h>
#include <math.h>

#define NN 50000
#define NE 500000
// D_IN=128, D_H=256, D_C=768, D_OUT=40

typedef __attribute__((ext_vector_type(8))) short short8;   // 8 bf16 (4 VGPRs)
typedef __attribute__((ext_vector_type(4))) float f32x4;    // MFMA acc

__device__ __forceinline__ float leaky02(float x) { return x > 0.f ? x : 0.2f * x; }
__device__ __forceinline__ ushort f2b(float f) {
    uint u = __float_as_uint(f);
    u += 0x7fffu + ((u >> 16) & 1u);          // RNE
    return (ushort)(u >> 16);
}
__device__ __forceinline__ float b2f(ushort h) { return __uint_as_float(((uint)h) << 16); }
__device__ __forceinline__ float b2f_lo(uint w) { return __uint_as_float(w << 16); }
__device__ __forceinline__ float b2f_hi(uint w) { return __uint_as_float(w & 0xffff0000u); }
__device__ __forceinline__ uint pack2(float a, float b) {
    return (uint)f2b(a) | ((uint)f2b(b) << 16);
}

// ---------------- W [K][Nc] fp32 -> Wt [Nc][K] bf16 ----------------
__global__ void mm_wt(const float* __restrict__ W, ushort* __restrict__ Wt, int K, int Nc)
{
    int idx = blockIdx.x * 256 + threadIdx.x;
    if (idx >= K * Nc) return;
    int n = idx / K, k = idx - n * K;
    Wt[idx] = f2b(W[(size_t)k * Nc + n]);
}

// ---------------- va = W_gat @ att_src, vd = W_gat @ att_dst (both [128]) ----------------
__global__ void mm_attvec(const float* __restrict__ W, const float* __restrict__ as_,
                          const float* __restrict__ ad_, float* __restrict__ va, float* __restrict__ vd)
{
    int i = threadIdx.x;           // 0..255
    const float* vec = (i < 128) ? as_ : ad_;
    int k = i & 127;
    float s = 0.f;
    for (int j = 0; j < 256; ++j) s += W[(size_t)k * 256 + j] * vec[j];
    if (i < 128) va[k] = s; else vd[k] = s;
}

// ---------------- fused: x fp32 -> xb bf16, es/ed = x.va / x.vd (wave per node) ----------------
__global__ __launch_bounds__(256) void mm_cvt_es(const float* __restrict__ x,
                                                 const float* __restrict__ va, const float* __restrict__ vd,
                                                 ushort* __restrict__ xb,
                                                 float* __restrict__ es, float* __restrict__ ed)
{
    int node = blockIdx.x * 4 + (threadIdx.x >> 6);
    int lane = threadIdx.x & 63;
    if (node >= NN) return;
    float2 xv = *(const float2*)(x + (size_t)node * 128 + lane * 2);
    float2 a = *(const float2*)(va + lane * 2);
    float2 b = *(const float2*)(vd + lane * 2);
    *(uint*)(xb + (size_t)node * 128 + lane * 2) = pack2(xv.x, xv.y);
    float s = xv.x * a.x + xv.y * a.y;
    float d = xv.x * b.x + xv.y * b.y;
    #pragma unroll
    for (int off = 32; off; off >>= 1) {
        s += __shfl_down(s, off);
        d += __shfl_down(d, off);
    }
    if (lane == 0) { es[node] = s; ed[node] = d; }
}

// ---------------- CSR build: count -> 3-phase scan -> fill ----------------
__global__ void mm_count(const int* __restrict__ dst, int* __restrict__ deg)
{
    int e = blockIdx.x * 256 + threadIdx.x;
    if (e >= NE) return;
    atomicAdd(&deg[dst[e]], 1);
}

__global__ __launch_bounds__(256) void mm_scan1(const int* __restrict__ deg, int* __restrict__ part)
{
    __shared__ int red[256];
    int i = blockIdx.x * 256 + threadIdx.x;
    red[threadIdx.x] = (i < NN) ? deg[i] : 0;
    __syncthreads();
    for (int off = 128; off; off >>= 1) {
        if (threadIdx.x < off) red[threadIdx.x] += red[threadIdx.x + off];
        __syncthreads();
    }
    if (threadIdx.x == 0) part[blockIdx.x] = red[0];
}

__global__ __launch_bounds__(256) void mm_scan2(int* __restrict__ part, int nb)
{
    __shared__ int tile[256];
    int t = threadIdx.x;
    int v = (t < nb) ? part[t] : 0;
    tile[t] = v; __syncthreads();
    for (int off = 1; off < 256; off <<= 1) {
        int a = (t >= off) ? tile[t - off] : 0;
        __syncthreads();
        tile[t] += a;
        __syncthreads();
    }
    if (t < nb) part[t] = tile[t] - v;   // exclusive
}

__global__ __launch_bounds__(256) void mm_scan3(const int* __restrict__ deg, const int* __restrict__ part,
                                                int* __restrict__ row_ptr, int* __restrict__ cursor)
{
    __shared__ int tile[256];
    int t = threadIdx.x;
    int i = blockIdx.x * 256 + t;
    int v = (i < NN) ? deg[i] : 0;
    tile[t] = v; __syncthreads();
    for (int off = 1; off < 256; off <<= 1) {
        int a = (t >= off) ? tile[t - off] : 0;
        __syncthreads();
        tile[t] += a;
        __syncthreads();
    }
    if (i < NN) {
        int ex = part[blockIdx.x] + tile[t] - v;
        row_ptr[i] = ex;
        cursor[i] = ex;
    }
    if (i == 0) row_ptr[NN] = NE;
}

__global__ void mm_fill(const int* __restrict__ src, const int* __restrict__ dst,
                        int* __restrict__ cursor, int* __restrict__ csr_src)
{
    int e = blockIdx.x * 256 + threadIdx.x;
    if (e >= NE) return;
    int pos = atomicAdd(&cursor[dst[e]], 1);
    csr_src[pos] = src[e];
}

__global__ void mm_dis(const int* __restrict__ row_ptr, float* __restrict__ dis)
{
    int i = blockIdx.x * 256 + threadIdx.x;
    if (i >= NN) return;
    dis[i] = rsqrtf((float)(row_ptr[i + 1] - row_ptr[i] + 1));
}

// ---------------- fused per-node: GAT softmax (in-reg) + GAT/GIN/GCN gather, wave per node ----------------
// aggb[d][0:128]=GAT, [128:256]=GIN(+self), [256:384]=GCN
__global__ __launch_bounds__(256) void mm_node_agg(
    const int* __restrict__ row_ptr, const int* __restrict__ csr_src,
    const float* __restrict__ es, const float* __restrict__ ed,
    const float* __restrict__ dis,
    const ushort* __restrict__ xb, ushort* __restrict__ aggb)
{
    int d = blockIdx.x * 4 + (threadIdx.x >> 6);
    int lane = threadIdx.x & 63;
    if (d >= NN) return;
    int start = row_ptr[d], end = row_ptr[d + 1];
    float edd = ed[d], disd = dis[d];
    float selfv = leaky02(es[d] + edd);

    // batch-0 edge data in registers (covers deg <= 64, i.e. essentially always)
    int myidx = -1; float myl = -3.0e38f, mynw = 0.f;
    if (start + lane < end) {
        myidx = csr_src[start + lane];
        myl = leaky02(es[myidx] + edd);
        mynw = dis[myidx] * disd;
    }
    float lmax = fmaxf(selfv, myl);
    for (int e = start + 64 + lane; e < end; e += 64)
        lmax = fmaxf(lmax, leaky02(es[csr_src[e]] + edd));
    #pragma unroll
    for (int off = 1; off < 64; off <<= 1) lmax = fmaxf(lmax, __shfl_xor(lmax, off));
    float m = lmax;

    float lsum = (myidx >= 0) ? __expf(myl - m) : 0.f;
    if (lane == 0) lsum += __expf(selfv - m);
    for (int e = start + 64 + lane; e < end; e += 64)
        lsum += __expf(leaky02(es[csr_src[e]] + edd) - m);
    #pragma unroll
    for (int off = 1; off < 64; off <<= 1) lsum += __shfl_xor(lsum, off);
    float inv = 1.f / lsum;
    float myal = __expf(myl - m) * inv;

    // self contributions
    float aself = __expf(selfv - m) * inv;
    float d2 = disd * disd;
    uint wself = *(const uint*)(xb + (size_t)d * 128 + lane * 2);
    float x0 = b2f_lo(wself), x1 = b2f_hi(wself);
    float gat0 = aself * x0, gat1 = aself * x1;
    float gin0 = x0, gin1 = x1;
    float gcn0 = d2 * x0, gcn1 = d2 * x1;

    for (int base = start; base < end; base += 64) {
        int cnt = min(64, end - base);
        int bidx; float bal, bnw;
        if (base == start) { bidx = myidx; bal = myal; bnw = mynw; }
        else {
            bidx = -1; bal = 0.f; bnw = 0.f;
            if (base + lane < end) {
                bidx = csr_src[base + lane];
                bal = __expf(leaky02(es[bidx] + edd) - m) * inv;
                bnw = dis[bidx] * disd;
            }
        }
        int j = 0;
        for (; j + 4 <= cnt; j += 4) {
            int   s0 = __shfl(bidx, j),     s1 = __shfl(bidx, j + 1);
            int   s2 = __shfl(bidx, j + 2), s3 = __shfl(bidx, j + 3);
            float a0 = __shfl(bal, j),      a1 = __shfl(bal, j + 1);
            float a2 = __shfl(bal, j + 2),  a3 = __shfl(bal, j + 3);
            float n0 = __shfl(bnw, j),      n1 = __shfl(bnw, j + 1);
            float n2 = __shfl(bnw, j + 2),  n3 = __shfl(bnw, j + 3);
            uint w0 = *(const uint*)(xb + (size_t)s0 * 128 + lane * 2);
            uint w1 = *(const uint*)(xb + (size_t)s1 * 128 + lane * 2);
            uint w2 = *(const uint*)(xb + (size_t)s2 * 128 + lane * 2);
            uint w3 = *(const uint*)(xb + (size_t)s3 * 128 + lane * 2);
            float p0, p1;
            p0 = b2f_lo(w0); p1 = b2f_hi(w0);
            gat0 += a0 * p0; gat1 += a0 * p1; gin0 += p0; gin1 += p1; gcn0 += n0 * p0; gcn1 += n0 * p1;
            p0 = b2f_lo(w1); p1 = b2f_hi(w1);
            gat0 += a1 * p0; gat1 += a1 * p1; gin0 += p0; gin1 += p1; gcn0 += n1 * p0; gcn1 += n1 * p1;
            p0 = b2f_lo(w2); p1 = b2f_hi(w2);
            gat0 += a2 * p0; gat1 += a2 * p1; gin0 += p0; gin1 += p1; gcn0 += n2 * p0; gcn1 += n2 * p1;
            p0 = b2f_lo(w3); p1 = b2f_hi(w3);
            gat0 += a3 * p0; gat1 += a3 * p1; gin0 += p0; gin1 += p1; gcn0 += n3 * p0; gcn1 += n3 * p1;
        }
        for (; j < cnt; ++j) {
            int   s0 = __shfl(bidx, j);
            float a0 = __shfl(bal, j);
            float n0 = __shfl(bnw, j);
            uint w0 = *(const uint*)(xb + (size_t)s0 * 128 + lane * 2);
            float p0 = b2f_lo(w0), p1 = b2f_hi(w0);
            gat0 += a0 * p0; gat1 += a0 * p1; gin0 += p0; gin1 += p1; gcn0 += n0 * p0; gcn1 += n0 * p1;
        }
    }
    ushort* orow = aggb + (size_t)d * 384;
    *(uint*)(orow + lane * 2)       = pack2(gat0, gat1);
    *(uint*)(orow + 128 + lane * 2) = pack2(gin0, gin1);
    *(uint*)(orow + 256 + lane * 2) = pack2(gcn0, gcn1);
}

// ---------------- bf16 MFMA GEMM: Cb = op(A @ Bt^T + bias), 128x128 tile ----------------
__global__ __launch_bounds__(256) void mm_gemm_bf(
    const ushort* __restrict__ A, int lda, const ushort* __restrict__ Bt,
    const float* __restrict__ bias,
    ushort* __restrict__ Cb, int ldc,
    int M, int K, int relu)
{
    __shared__ ushort lds[8192];            // As[128][32] | Bs[128][32]
    const int tid = threadIdx.x;
    const int wave = tid >> 6, lane = tid & 63;
    const int row0 = blockIdx.x * 128;
    const int col0 = blockIdx.y * 128;

    int arow0 = min(row0 + wave * 16 + (lane >> 2), M - 1);
    int arow1 = min(row0 + 64 + wave * 16 + (lane >> 2), M - 1);
    int brow0 = col0 + wave * 16 + (lane >> 2);
    int brow1 = col0 + 64 + wave * 16 + (lane >> 2);
    const ushort* pa0 = A + (size_t)arow0 * lda + (lane & 3) * 8;
    const ushort* pa1 = A + (size_t)arow1 * lda + (lane & 3) * 8;
    const ushort* pb0 = Bt + (size_t)brow0 * K + (lane & 3) * 8;
    const ushort* pb1 = Bt + (size_t)brow1 * K + (lane & 3) * 8;

    ushort* As = lds;
    ushort* Bs = lds + 4096;
    const int wr = (wave >> 1) * 64, wc = (wave & 1) * 64;

    f32x4 zero = {0.f, 0.f, 0.f, 0.f};
    f32x4 acc[4][4];
    #pragma unroll
    for (int m = 0; m < 4; ++m)
        #pragma unroll
        for (int n = 0; n < 4; ++n) acc[m][n] = zero;

    for (int k0 = 0; k0 < K; k0 += 32) {
        __builtin_amdgcn_global_load_lds((const __attribute__((address_space(1))) void*)pa0,
            (__attribute__((address_space(3))) void*)(As + wave * 512), 16, 0, 0);
        __builtin_amdgcn_global_load_lds((const __attribute__((address_space(1))) void*)pa1,
            (__attribute__((address_space(3))) void*)(As + 2048 + wave * 512), 16, 0, 0);
        __builtin_amdgcn_global_load_lds((const __attribute__((address_space(1))) void*)pb0,
            (__attribute__((address_space(3))) void*)(Bs + wave * 512), 16, 0, 0);
        __builtin_amdgcn_global_load_lds((const __attribute__((address_space(1))) void*)pb1,
            (__attribute__((address_space(3))) void*)(Bs + 2048 + wave * 512), 16, 0, 0);
        pa0 += 32; pa1 += 32; pb0 += 32; pb1 += 32;
        __syncthreads();

        short8 a[4], b[4];
        #pragma unroll
        for (int m = 0; m < 4; ++m)
            a[m] = *(const short8*)&As[(wr + m * 16 + (lane & 15)) * 32 + (lane >> 4) * 8];
        #pragma unroll
        for (int n = 0; n < 4; ++n)
            b[n] = *(const short8*)&Bs[(wc + n * 16 + (lane & 15)) * 32 + (lane >> 4) * 8];
        #pragma unroll
        for (int m = 0; m < 4; ++m)
            #pragma unroll
            for (int n = 0; n < 4; ++n)
                acc[m][n] = __builtin_amdgcn_mfma_f32_16x16x32_bf16(a[m], b[n], acc[m][n], 0, 0, 0);
        __syncthreads();
    }

    #pragma unroll
    for (int n = 0; n < 4; ++n) {
        int col = col0 + wc + n * 16 + (lane & 15);
        float bb = bias ? bias[col] : 0.f;
        #pragma unroll
        for (int m = 0; m < 4; ++m) {
            int rb = row0 + wr + m * 16 + (lane >> 4) * 4;
            #pragma unroll
            for (int r = 0; r < 4; ++r) {
                int row = rb + r;
                if (row < M) {
                    float v = acc[m][n][r] + bb;
                    if (relu) v = fmaxf(v, 0.f);
                    Cb[(size_t)row * ldc + col] = f2b(v);
                }
            }
        }
    }
}

// ---------------- head GEMM with fused BN+ReLU on A: Cb = relu(relu(A*sc+sh) @ Bt^T + bias) ----------------
// A: [M][768] bf16 (xcb raw); sc/sh per K-channel; reg-staged A -> LDS.
__global__ __launch_bounds__(256) void mm_gemm_bn(
    const ushort* __restrict__ A, const ushort* __restrict__ Bt,
    const float* __restrict__ bias,
    const float* __restrict__ sc, const float* __restrict__ sh,
    ushort* __restrict__ Cb, int ldc, int M)
{
    const int K = 768, lda = 768;
    __shared__ ushort lds[8192];
    const int tid = threadIdx.x;
    const int wave = tid >> 6, lane = tid & 63;
    const int row0 = blockIdx.x * 128;
    const int col0 = blockIdx.y * 128;

    int arow0 = min(row0 + wave * 16 + (lane >> 2), M - 1);
    int arow1 = min(row0 + 64 + wave * 16 + (lane >> 2), M - 1);
    int brow0 = col0 + wave * 16 + (lane >> 2);
    int brow1 = col0 + 64 + wave * 16 + (lane >> 2);
    const ushort* pa0 = A + (size_t)arow0 * lda + (lane & 3) * 8;
    const ushort* pa1 = A + (size_t)arow1 * lda + (lane & 3) * 8;
    const ushort* pb0 = Bt + (size_t)brow0 * K + (lane & 3) * 8;
    const ushort* pb1 = Bt + (size_t)brow1 * K + (lane & 3) * 8;

    ushort* As = lds;
    ushort* Bs = lds + 4096;
    const int wr = (wave >> 1) * 64, wc = (wave & 1) * 64;

    f32x4 zero = {0.f, 0.f, 0.f, 0.f};
    f32x4 acc[4][4];
    #pragma unroll
    for (int m = 0; m < 4; ++m)
        #pragma unroll
        for (int n = 0; n < 4; ++n) acc[m][n] = zero;

    for (int k0 = 0; k0 < K; k0 += 32) {
        // B: async to LDS
        __builtin_amdgcn_global_load_lds((const __attribute__((address_space(1))) void*)pb0,
            (__attribute__((address_space(3))) void*)(Bs + wave * 512), 16, 0, 0);
        __builtin_amdgcn_global_load_lds((const __attribute__((address_space(1))) void*)pb1,
            (__attribute__((address_space(3))) void*)(Bs + 2048 + wave * 512), 16, 0, 0);
        // A: regs -> BN+ReLU -> LDS
        uint4 w0 = *(const uint4*)pa0;
        uint4 w1 = *(const uint4*)pa1;
        int c = k0 + (lane & 3) * 8;
        float4 sc0 = *(const float4*)(sc + c), sc1 = *(const float4*)(sc + c + 4);
        float4 sh0 = *(const float4*)(sh + c), sh1 = *(const float4*)(sh + c + 4);
        uint o0x = pack2(fmaxf(b2f_lo(w0.x) * sc0.x + sh0.x, 0.f), fmaxf(b2f_hi(w0.x) * sc0.y + sh0.y, 0.f));
        uint o0y = pack2(fmaxf(b2f_lo(w0.y) * sc0.z + sh0.z, 0.f), fmaxf(b2f_hi(w0.y) * sc0.w + sh0.w, 0.f));
        uint o0z = pack2(fmaxf(b2f_lo(w0.z) * sc1.x + sh1.x, 0.f), fmaxf(b2f_hi(w0.z) * sc1.y + sh1.y, 0.f));
        uint o0w = pack2(fmaxf(b2f_lo(w0.w) * sc1.z + sh1.z, 0.f), fmaxf(b2f_hi(w0.w) * sc1.w + sh1.w, 0.f));
        uint o1x = pack2(fmaxf(b2f_lo(w1.x) * sc0.x + sh0.x, 0.f), fmaxf(b2f_hi(w1.x) * sc0.y + sh0.y, 0.f));
        uint o1y = pack2(fmaxf(b2f_lo(w1.y) * sc0.z + sh0.z, 0.f), fmaxf(b2f_hi(w1.y) * sc0.w + sh0.w, 0.f));
        uint o1z = pack2(fmaxf(b2f_lo(w1.z) * sc1.x + sh1.x, 0.f), fmaxf(b2f_hi(w1.z) * sc1.y + sh1.y, 0.f));
        uint o1w = pack2(fmaxf(b2f_lo(w1.w) * sc1.z + sh1.z, 0.f), fmaxf(b2f_hi(w1.w) * sc1.w + sh1.w, 0.f));
        uint4 oa = {o0x, o0y, o0z, o0w};
        uint4 ob = {o1x, o1y, o1z, o1w};
        *(uint4*)(As + wave * 512 + lane * 8) = oa;
        *(uint4*)(As + 2048 + wave * 512 + lane * 8) = ob;
        pa0 += 32; pa1 += 32; pb0 += 32; pb1 += 32;
        __syncthreads();

        short8 a[4], b[4];
        #pragma unroll
        for (int m = 0; m < 4; ++m)
            a[m] = *(const short8*)&As[(wr + m * 16 + (lane & 15)) * 32 + (lane >> 4) * 8];
        #pragma unroll
        for (int n = 0; n < 4; ++n)
            b[n] = *(const short8*)&Bs[(wc + n * 16 + (lane & 15)) * 32 + (lane >> 4) * 8];
        #pragma unroll
        for (int m = 0; m < 4; ++m)
            #pragma unroll
            for (int n = 0; n < 4; ++n)
                acc[m][n] = __builtin_amdgcn_mfma_f32_16x16x32_bf16(a[m], b[n], acc[m][n], 0, 0, 0);
        __syncthreads();
    }

    #pragma unroll
    for (int n = 0; n < 4; ++n) {
        int col = col0 + wc + n * 16 + (lane & 15);
        float bb = bias[col];
        #pragma unroll
        for (int m = 0; m < 4; ++m) {
            int rb = row0 + wr + m * 16 + (lane >> 4) * 4;
            #pragma unroll
            for (int r = 0; r < 4; ++r) {
                int row = rb + r;
                if (row < M)
                    Cb[(size_t)row * ldc + col] = f2b(fmaxf(acc[m][n][r] + bb, 0.f));
            }
        }
    }
}

// ---------------- BatchNorm stats (bf16 input, 2 cols/thread) ----------------
__global__ __launch_bounds__(384) void mm_bn_partial(const ushort* __restrict__ xcb, float* __restrict__ sums)
{
    int r0 = blockIdx.x * 128;
    int rend = min(r0 + 128, NN);
    int t = threadIdx.x;           // cols 2t, 2t+1
    float s0 = 0, q0 = 0, s1 = 0, q1 = 0;
    for (int r = r0; r < rend; ++r) {
        uint w = *(const uint*)(xcb + (size_t)r * 768 + 2 * t);
        float v0 = b2f_lo(w), v1 = b2f_hi(w);
        s0 += v0; q0 += v0 * v0;
        s1 += v1; q1 += v1 * v1;
    }
    unsafeAtomicAdd(&sums[2 * t], s0);
    unsafeAtomicAdd(&sums[2 * t + 1], s1);
    unsafeAtomicAdd(&sums[768 + 2 * t], q0);
    unsafeAtomicAdd(&sums[768 + 2 * t + 1], q1);
}

__global__ void mm_bn_fin(const float* __restrict__ sums, const float* __restrict__ gamma,
                          const float* __restrict__ beta,
                          float* __restrict__ scale, float* __restrict__ shift)
{
    int c = blockIdx.x * 256 + threadIdx.x;
    if (c >= 768) return;
    float inv = 1.f / (float)NN;
    float mu = sums[c] * inv;
    float ex2 = sums[768 + c] * inv;
    float var = fmaxf(ex2 - mu * mu, 0.f);
    float rs = rsqrtf(var + 1e-5f);
    float sc = gamma[c] * rs;
    scale[c] = sc;
    shift[c] = beta[c] - mu * sc;
}

// ---------------- out = h2 @ W2 + b2 (h2 bf16 [NN,256], W2 fp32 [256,40]) ----------------
__global__ __launch_bounds__(256) void mm_head2(const ushort* __restrict__ h2b, const float* __restrict__ W2,
                                                const float* __restrict__ b2, float* __restrict__ out)
{
    __shared__ float Ws[256 * 40];
    for (int i = threadIdx.x; i < 256 * 40; i += 256) Ws[i] = W2[i];
    __syncthreads();
    int row = blockIdx.x * 32 + (threadIdx.x >> 3);
    int cg = (threadIdx.x & 7) * 5;
    if (row >= NN) return;
    const ushort* hr = h2b + (size_t)row * 256;
    float acc[5] = {0, 0, 0, 0, 0};
    for (int k = 0; k < 256; k += 8) {
        uint4 w = *(const uint4*)(hr + k);
        float a0 = b2f_lo(w.x), a1 = b2f_hi(w.x), a2 = b2f_lo(w.y), a3 = b2f_hi(w.y);
        float a4 = b2f_lo(w.z), a5 = b2f_hi(w.z), a6 = b2f_lo(w.w), a7 = b2f_hi(w.w);
        #pragma unroll
        for (int j = 0; j < 5; ++j) {
            acc[j] += a0 * Ws[(k + 0) * 40 + cg + j] + a1 * Ws[(k + 1) * 40 + cg + j]
                    + a2 * Ws[(k + 2) * 40 + cg + j] + a3 * Ws[(k + 3) * 40 + cg + j]
                    + a4 * Ws[(k + 4) * 40 + cg + j] + a5 * Ws[(k + 5) * 40 + cg + j]
                    + a6 * Ws[(k + 6) * 40 + cg + j] + a7 * Ws[(k + 7) * 40 + cg + j];
        }
    }
    #pragma unroll
    for (int j = 0; j < 5; ++j) out[(size_t)row * 40 + cg + j] = acc[j] + b2[cg + j];
}

extern "C" void kernel_launch(void* const* d_in, const int* in_sizes, int n_in,
                              void* d_out, int out_size, void* d_ws, size_t ws_size,
                              hipStream_t stream)
{
    const float* x      = (const float*)d_in[0];
    const int*   ei     = (const int*)d_in[1];
    const float* W_gat  = (const float*)d_in[2];
    const float* att_s  = (const float*)d_in[3];
    const float* att_d  = (const float*)d_in[4];
    const float* b_gat  = (const float*)d_in[5];
    const float* W_gin1 = (const float*)d_in[6];
    const float* b_gin1 = (const float*)d_in[7];
    const float* W_gin2 = (const float*)d_in[8];
    const float* b_gin2 = (const float*)d_in[9];
    const float* W_gcn  = (const float*)d_in[10];
    const float* b_gcn  = (const float*)d_in[11];
    const float* gamma  = (const float*)d_in[12];
    const float* beta   = (const float*)d_in[13];
    const float* W_lin  = (const float*)d_in[14];
    const float* b_lin  = (const float*)d_in[15];
    const float* W_lin2 = (const float*)d_in[16];
    const float* b_lin2 = (const float*)d_in[17];
    const int* src = ei;
    const int* dst = ei + NE;
    float* out = (float*)d_out;

    float* ws = (float*)d_ws;
    size_t off = 0;
    ushort* xb      = (ushort*)(ws + off); off += (size_t)NN * 64;    // [NN][128] bf16
    ushort* aggb    = (ushort*)(ws + off); off += (size_t)NN * 192;   // [NN][384] bf16: gat|gin|gcn
    ushort* hid_b   = (ushort*)(ws + off); off += (size_t)NN * 128;   // GIN hidden; later h2
    ushort* xcb     = (ushort*)(ws + off); off += (size_t)NN * 384;   // [NN][768] bf16
    float* es       = ws + off; off += NN;
    float* ed       = ws + off; off += NN;
    float* dis      = ws + off; off += NN;
    float* va       = ws + off; off += 128;
    float* vd       = ws + off; off += 128;
    float* bnsum    = ws + off; off += 1536;
    float* bscale   = ws + off; off += 768;
    float* bshift   = ws + off; off += 768;
    ushort* wt_gat  = (ushort*)(ws + off); off += 128 * 256 / 2;
    ushort* wt_gin1 = (ushort*)(ws + off); off += 128 * 256 / 2;
    ushort* wt_gin2 = (ushort*)(ws + off); off += 256 * 256 / 2;
    ushort* wt_gcn  = (ushort*)(ws + off); off += 128 * 256 / 2;
    ushort* wt_lin  = (ushort*)(ws + off); off += 768 * 256 / 2;
    int* part       = (int*)(ws + off); off += 256;
    int* row_ptr    = (int*)(ws + off); off += NN + 1;
    int* cursor     = (int*)(ws + off); off += NN;
    int* csr_src    = (int*)(ws + off); off += NE;

    dim3 blk(256);
    dim3 gemm_grid((NN + 127) / 128, 2);   // N=256 -> 2 col blocks
    const int NB = (NN + 255) / 256;       // scan tiles

    // ---- weight transposes / attention vectors ----
    mm_wt<<<(128 * 256 + 255) / 256, blk, 0, stream>>>(W_gat, wt_gat, 128, 256);
    mm_wt<<<(128 * 256 + 255) / 256, blk, 0, stream>>>(W_gin1, wt_gin1, 128, 256);
    mm_wt<<<(256 * 256 + 255) / 256, blk, 0, stream>>>(W_gin2, wt_gin2, 256, 256);
    mm_wt<<<(128 * 256 + 255) / 256, blk, 0, stream>>>(W_gcn, wt_gcn, 128, 256);
    mm_wt<<<(768 * 256 + 255) / 256, blk, 0, stream>>>(W_lin, wt_lin, 768, 256);
    mm_attvec<<<1, blk, 0, stream>>>(W_gat, att_s, att_d, va, vd);

    // ---- fused convert + attention dots ----
    mm_cvt_es<<<(NN + 3) / 4, blk, 0, stream>>>(x, va, vd, xb, es, ed);

    // ---- CSR build ----
    hipMemsetAsync(cursor, 0, NN * sizeof(int), stream);
    mm_count<<<(NE + 255) / 256, blk, 0, stream>>>(dst, cursor);
    mm_scan1<<<NB, blk, 0, stream>>>(cursor, part);
    mm_scan2<<<1, blk, 0, stream>>>(part, NB);
    mm_scan3<<<NB, blk, 0, stream>>>(cursor, part, row_ptr, cursor);
    mm_dis<<<(NN + 255) / 256, blk, 0, stream>>>(row_ptr, dis);
    mm_fill<<<(NE + 255) / 256, blk, 0, stream>>>(src, dst, cursor, csr_src);

    // ---- fused per-node softmax + 3-way gather ----
    mm_node_agg<<<(NN + 3) / 4, blk, 0, stream>>>(row_ptr, csr_src, es, ed, dis, xb, aggb);

    // ---- GEMMs ----
    mm_gemm_bf<<<gemm_grid, blk, 0, stream>>>(aggb,       384, wt_gat,  b_gat,  xcb,       768, NN, 128, 0);
    mm_gemm_bf<<<gemm_grid, blk, 0, stream>>>(aggb + 128, 384, wt_gin1, b_gin1, hid_b,     256, NN, 128, 1);
    mm_gemm_bf<<<gemm_grid, blk, 0, stream>>>(hid_b,      256, wt_gin2, b_gin2, xcb + 256, 768, NN, 256, 0);
    mm_gemm_bf<<<gemm_grid, blk, 0, stream>>>(aggb + 256, 384, wt_gcn,  b_gcn,  xcb + 512, 768, NN, 128, 0);

    // ---- BatchNorm stats ----
    hipMemsetAsync(bnsum, 0, 1536 * sizeof(float), stream);
    mm_bn_partial<<<(NN + 127) / 128, dim3(384), 0, stream>>>(xcb, bnsum);
    mm_bn_fin<<<3, blk, 0, stream>>>(bnsum, gamma, beta, bscale, bshift);

    // ---- head: BN+ReLU fused into A staging ----
    mm_gemm_bn<<<gemm_grid, blk, 0, stream>>>(xcb, wt_lin, b_lin, bscale, bshift, hid_b, 256, NN);
    mm_head2<<<(NN + 31) / 32, blk, 0, stream>>>(hid_b, W_lin2, b_lin2, out);
}

// Round 6
// 419.155 us; speedup vs baseline: 12.0216x; 1.0278x over previous
//
#include <hip/hip_runtime.h>
#include <math.h>

#define NN 50000
#define NE 500000
// D_IN=128, D_H=256, D_C=768, D_OUT=40

typedef __attribute__((ext_vector_type(8))) short short8;   // 8 bf16 (4 VGPRs)
typedef __attribute__((ext_vector_type(4))) float f32x4;    // MFMA acc

__device__ __forceinline__ float leaky02(float x) { return x > 0.f ? x : 0.2f * x; }
__device__ __forceinline__ ushort f2b(float f) {
    uint u = __float_as_uint(f);
    u += 0x7fffu + ((u >> 16) & 1u);          // RNE
    return (ushort)(u >> 16);
}
__device__ __forceinline__ float b2f(ushort h) { return __uint_as_float(((uint)h) << 16); }
__device__ __forceinline__ float b2f_lo(uint w) { return __uint_as_float(w << 16); }
__device__ __forceinline__ float b2f_hi(uint w) { return __uint_as_float(w & 0xffff0000u); }
__device__ __forceinline__ uint pack2(float a, float b) {
    return (uint)f2b(a) | ((uint)f2b(b) << 16);
}

// ---------------- W [K][Nc] fp32 -> Wt [Nc][K] bf16 ----------------
__global__ void mm_wt(const float* __restrict__ W, ushort* __restrict__ Wt, int K, int Nc)
{
    int idx = blockIdx.x * 256 + threadIdx.x;
    if (idx >= K * Nc) return;
    int n = idx / K, k = idx - n * K;
    Wt[idx] = f2b(W[(size_t)k * Nc + n]);
}

// ---------------- va = W_gat @ att_src, vd = W_gat @ att_dst (both [128]) ----------------
__global__ void mm_attvec(const float* __restrict__ W, const float* __restrict__ as_,
                          const float* __restrict__ ad_, float* __restrict__ va, float* __restrict__ vd)
{
    int i = threadIdx.x;           // 0..255
    const float* vec = (i < 128) ? as_ : ad_;
    int k = i & 127;
    float s = 0.f;
    for (int j = 0; j < 256; ++j) s += W[(size_t)k * 256 + j] * vec[j];
    if (i < 128) va[k] = s; else vd[k] = s;
}

// ---------------- fused: x fp32 -> xb bf16, es/ed = x.va / x.vd (wave per node) ----------------
__global__ __launch_bounds__(256) void mm_cvt_es(const float* __restrict__ x,
                                                 const float* __restrict__ va, const float* __restrict__ vd,
                                                 ushort* __restrict__ xb,
                                                 float* __restrict__ es, float* __restrict__ ed)
{
    int node = blockIdx.x * 4 + (threadIdx.x >> 6);
    int lane = threadIdx.x & 63;
    if (node >= NN) return;
    float2 xv = *(const float2*)(x + (size_t)node * 128 + lane * 2);
    float2 a = *(const float2*)(va + lane * 2);
    float2 b = *(const float2*)(vd + lane * 2);
    *(uint*)(xb + (size_t)node * 128 + lane * 2) = pack2(xv.x, xv.y);
    float s = xv.x * a.x + xv.y * a.y;
    float d = xv.x * b.x + xv.y * b.y;
    #pragma unroll
    for (int off = 32; off; off >>= 1) {
        s += __shfl_down(s, off);
        d += __shfl_down(d, off);
    }
    if (lane == 0) { es[node] = s; ed[node] = d; }
}

// ---------------- CSR build: count -> 3-phase scan -> fill ----------------
__global__ void mm_count(const int* __restrict__ dst, int* __restrict__ deg)
{
    int e = blockIdx.x * 256 + threadIdx.x;
    if (e >= NE) return;
    atomicAdd(&deg[dst[e]], 1);
}

__global__ __launch_bounds__(256) void mm_scan1(const int* __restrict__ deg, int* __restrict__ part)
{
    __shared__ int red[256];
    int i = blockIdx.x * 256 + threadIdx.x;
    red[threadIdx.x] = (i < NN) ? deg[i] : 0;
    __syncthreads();
    for (int off = 128; off; off >>= 1) {
        if (threadIdx.x < off) red[threadIdx.x] += red[threadIdx.x + off];
        __syncthreads();
    }
    if (threadIdx.x == 0) part[blockIdx.x] = red[0];
}

__global__ __launch_bounds__(256) void mm_scan2(int* __restrict__ part, int nb)
{
    __shared__ int tile[256];
    int t = threadIdx.x;
    int v = (t < nb) ? part[t] : 0;
    tile[t] = v; __syncthreads();
    for (int off = 1; off < 256; off <<= 1) {
        int a = (t >= off) ? tile[t - off] : 0;
        __syncthreads();
        tile[t] += a;
        __syncthreads();
    }
    if (t < nb) part[t] = tile[t] - v;   // exclusive
}

__global__ __launch_bounds__(256) void mm_scan3(const int* __restrict__ deg, const int* __restrict__ part,
                                                int* __restrict__ row_ptr, int* __restrict__ cursor)
{
    __shared__ int tile[256];
    int t = threadIdx.x;
    int i = blockIdx.x * 256 + t;
    int v = (i < NN) ? deg[i] : 0;
    tile[t] = v; __syncthreads();
    for (int off = 1; off < 256; off <<= 1) {
        int a = (t >= off) ? tile[t - off] : 0;
        __syncthreads();
        tile[t] += a;
        __syncthreads();
    }
    if (i < NN) {
        int ex = part[blockIdx.x] + tile[t] - v;
        row_ptr[i] = ex;
        cursor[i] = ex;
    }
    if (i == 0) row_ptr[NN] = NE;
}

__global__ void mm_fill(const int* __restrict__ src, const int* __restrict__ dst,
                        int* __restrict__ cursor, int* __restrict__ csr_src)
{
    int e = blockIdx.x * 256 + threadIdx.x;
    if (e >= NE) return;
    int pos = atomicAdd(&cursor[dst[e]], 1);
    csr_src[pos] = src[e];
}

__global__ void mm_dis(const int* __restrict__ row_ptr, float* __restrict__ dis)
{
    int i = blockIdx.x * 256 + threadIdx.x;
    if (i >= NN) return;
    dis[i] = rsqrtf((float)(row_ptr[i + 1] - row_ptr[i] + 1));
}

// ---------------- fused per-node: GAT softmax (in-reg) + GAT/GIN/GCN gather, wave per node ----------------
__global__ __launch_bounds__(256) void mm_node_agg(
    const int* __restrict__ row_ptr, const int* __restrict__ csr_src,
    const float* __restrict__ es, const float* __restrict__ ed,
    const float* __restrict__ dis,
    const ushort* __restrict__ xb, ushort* __restrict__ aggb)
{
    int d = blockIdx.x * 4 + (threadIdx.x >> 6);
    int lane = threadIdx.x & 63;
    if (d >= NN) return;
    int start = row_ptr[d], end = row_ptr[d + 1];
    float edd = ed[d], disd = dis[d];
    float selfv = leaky02(es[d] + edd);

    int myidx = -1; float myl = -3.0e38f, mynw = 0.f;
    if (start + lane < end) {
        myidx = csr_src[start + lane];
        myl = leaky02(es[myidx] + edd);
        mynw = dis[myidx] * disd;
    }
    float lmax = fmaxf(selfv, myl);
    for (int e = start + 64 + lane; e < end; e += 64)
        lmax = fmaxf(lmax, leaky02(es[csr_src[e]] + edd));
    #pragma unroll
    for (int off = 1; off < 64; off <<= 1) lmax = fmaxf(lmax, __shfl_xor(lmax, off));
    float m = lmax;

    float lsum = (myidx >= 0) ? __expf(myl - m) : 0.f;
    if (lane == 0) lsum += __expf(selfv - m);
    for (int e = start + 64 + lane; e < end; e += 64)
        lsum += __expf(leaky02(es[csr_src[e]] + edd) - m);
    #pragma unroll
    for (int off = 1; off < 64; off <<= 1) lsum += __shfl_xor(lsum, off);
    float inv = 1.f / lsum;
    float myal = __expf(myl - m) * inv;

    float aself = __expf(selfv - m) * inv;
    float d2 = disd * disd;
    uint wself = *(const uint*)(xb + (size_t)d * 128 + lane * 2);
    float x0 = b2f_lo(wself), x1 = b2f_hi(wself);
    float gat0 = aself * x0, gat1 = aself * x1;
    float gin0 = x0, gin1 = x1;
    float gcn0 = d2 * x0, gcn1 = d2 * x1;

    for (int base = start; base < end; base += 64) {
        int cnt = min(64, end - base);
        int bidx; float bal, bnw;
        if (base == start) { bidx = myidx; bal = myal; bnw = mynw; }
        else {
            bidx = -1; bal = 0.f; bnw = 0.f;
            if (base + lane < end) {
                bidx = csr_src[base + lane];
                bal = __expf(leaky02(es[bidx] + edd) - m) * inv;
                bnw = dis[bidx] * disd;
            }
        }
        int j = 0;
        for (; j + 4 <= cnt; j += 4) {
            int   s0 = __shfl(bidx, j),     s1 = __shfl(bidx, j + 1);
            int   s2 = __shfl(bidx, j + 2), s3 = __shfl(bidx, j + 3);
            float a0 = __shfl(bal, j),      a1 = __shfl(bal, j + 1);
            float a2 = __shfl(bal, j + 2),  a3 = __shfl(bal, j + 3);
            float n0 = __shfl(bnw, j),      n1 = __shfl(bnw, j + 1);
            float n2 = __shfl(bnw, j + 2),  n3 = __shfl(bnw, j + 3);
            uint w0 = *(const uint*)(xb + (size_t)s0 * 128 + lane * 2);
            uint w1 = *(const uint*)(xb + (size_t)s1 * 128 + lane * 2);
            uint w2 = *(const uint*)(xb + (size_t)s2 * 128 + lane * 2);
            uint w3 = *(const uint*)(xb + (size_t)s3 * 128 + lane * 2);
            float p0, p1;
            p0 = b2f_lo(w0); p1 = b2f_hi(w0);
            gat0 += a0 * p0; gat1 += a0 * p1; gin0 += p0; gin1 += p1; gcn0 += n0 * p0; gcn1 += n0 * p1;
            p0 = b2f_lo(w1); p1 = b2f_hi(w1);
            gat0 += a1 * p0; gat1 += a1 * p1; gin0 += p0; gin1 += p1; gcn0 += n1 * p0; gcn1 += n1 * p1;
            p0 = b2f_lo(w2); p1 = b2f_hi(w2);
            gat0 += a2 * p0; gat1 += a2 * p1; gin0 += p0; gin1 += p1; gcn0 += n2 * p0; gcn1 += n2 * p1;
            p0 = b2f_lo(w3); p1 = b2f_hi(w3);
            gat0 += a3 * p0; gat1 += a3 * p1; gin0 += p0; gin1 += p1; gcn0 += n3 * p0; gcn1 += n3 * p1;
        }
        for (; j < cnt; ++j) {
            int   s0 = __shfl(bidx, j);
            float a0 = __shfl(bal, j);
            float n0 = __shfl(bnw, j);
            uint w0 = *(const uint*)(xb + (size_t)s0 * 128 + lane * 2);
            float p0 = b2f_lo(w0), p1 = b2f_hi(w0);
            gat0 += a0 * p0; gat1 += a0 * p1; gin0 += p0; gin1 += p1; gcn0 += n0 * p0; gcn1 += n0 * p1;
        }
    }
    ushort* orow = aggb + (size_t)d * 384;
    *(uint*)(orow + lane * 2)       = pack2(gat0, gat1);
    *(uint*)(orow + 128 + lane * 2) = pack2(gin0, gin1);
    *(uint*)(orow + 256 + lane * 2) = pack2(gcn0, gcn1);
}

// ---------------- bf16 MFMA GEMM, 2-phase double-buffered staging ----------------
// Cb = op(A @ Bt^T + bias); optional per-column sum/sumsq accumulation (BN stats).
// stats (if non-null): stats[col] += v, stats[768+col] += v*v  (col = local 0..255)
__global__ __launch_bounds__(256) void mm_gemm_bf(
    const ushort* __restrict__ A, int lda, const ushort* __restrict__ Bt,
    const float* __restrict__ bias, float* __restrict__ stats,
    ushort* __restrict__ Cb, int ldc,
    int M, int K, int relu)
{
    __shared__ ushort lds[16384];           // 2 × (As[128][32] | Bs[128][32])
    const int tid = threadIdx.x;
    const int wave = tid >> 6, lane = tid & 63;
    const int row0 = blockIdx.x * 128;
    const int col0 = blockIdx.y * 128;

    int arow0 = min(row0 + wave * 16 + (lane >> 2), M - 1);
    int arow1 = min(row0 + 64 + wave * 16 + (lane >> 2), M - 1);
    int brow0 = col0 + wave * 16 + (lane >> 2);
    int brow1 = col0 + 64 + wave * 16 + (lane >> 2);
    const ushort* pa0 = A + (size_t)arow0 * lda + (lane & 3) * 8;
    const ushort* pa1 = A + (size_t)arow1 * lda + (lane & 3) * 8;
    const ushort* pb0 = Bt + (size_t)brow0 * K + (lane & 3) * 8;
    const ushort* pb1 = Bt + (size_t)brow1 * K + (lane & 3) * 8;
    const int wr = (wave >> 1) * 64, wc = (wave & 1) * 64;

    f32x4 zero = {0.f, 0.f, 0.f, 0.f};
    f32x4 acc[4][4];
    #pragma unroll
    for (int m = 0; m < 4; ++m)
        #pragma unroll
        for (int n = 0; n < 4; ++n) acc[m][n] = zero;

    const int nt = K >> 5;

#define STAGE_BF(bufi) { \
    ushort* Lb = lds + (bufi) * 8192; \
    __builtin_amdgcn_global_load_lds((const __attribute__((address_space(1))) void*)pa0, \
        (__attribute__((address_space(3))) void*)(Lb + wave * 512), 16, 0, 0); \
    __builtin_amdgcn_global_load_lds((const __attribute__((address_space(1))) void*)pa1, \
        (__attribute__((address_space(3))) void*)(Lb + 2048 + wave * 512), 16, 0, 0); \
    __builtin_amdgcn_global_load_lds((const __attribute__((address_space(1))) void*)pb0, \
        (__attribute__((address_space(3))) void*)(Lb + 4096 + wave * 512), 16, 0, 0); \
    __builtin_amdgcn_global_load_lds((const __attribute__((address_space(1))) void*)pb1, \
        (__attribute__((address_space(3))) void*)(Lb + 6144 + wave * 512), 16, 0, 0); \
    pa0 += 32; pa1 += 32; pb0 += 32; pb1 += 32; }

    STAGE_BF(0);
    __syncthreads();
    for (int t = 0; t < nt; ++t) {
        int cur = t & 1;
        if (t + 1 < nt) STAGE_BF(cur ^ 1);
        const ushort* As = lds + cur * 8192;
        const ushort* Bs = As + 4096;
        short8 a[4], b[4];
        #pragma unroll
        for (int m = 0; m < 4; ++m)
            a[m] = *(const short8*)&As[(wr + m * 16 + (lane & 15)) * 32 + (lane >> 4) * 8];
        #pragma unroll
        for (int n = 0; n < 4; ++n)
            b[n] = *(const short8*)&Bs[(wc + n * 16 + (lane & 15)) * 32 + (lane >> 4) * 8];
        #pragma unroll
        for (int m = 0; m < 4; ++m)
            #pragma unroll
            for (int n = 0; n < 4; ++n)
                acc[m][n] = __builtin_amdgcn_mfma_f32_16x16x32_bf16(a[m], b[n], acc[m][n], 0, 0, 0);
        if (t + 1 < nt) __syncthreads();
    }
#undef STAGE_BF

    // epilogue: C/D layout col=lane&15, row=(lane>>4)*4+reg
    #pragma unroll
    for (int n = 0; n < 4; ++n) {
        int col = col0 + wc + n * 16 + (lane & 15);   // local col 0..255
        float bb = bias ? bias[col] : 0.f;
        float s_acc = 0.f, q_acc = 0.f;
        #pragma unroll
        for (int m = 0; m < 4; ++m) {
            int rb = row0 + wr + m * 16 + (lane >> 4) * 4;
            #pragma unroll
            for (int r = 0; r < 4; ++r) {
                int row = rb + r;
                if (row < M) {
                    float v = acc[m][n][r] + bb;
                    if (relu) v = fmaxf(v, 0.f);
                    Cb[(size_t)row * ldc + col] = f2b(v);
                    s_acc += v; q_acc += v * v;
                }
            }
        }
        if (stats) {
            s_acc += __shfl_xor(s_acc, 16); q_acc += __shfl_xor(q_acc, 16);
            s_acc += __shfl_xor(s_acc, 32); q_acc += __shfl_xor(q_acc, 32);
            if (lane < 16) {
                unsafeAtomicAdd(&stats[col], s_acc);
                unsafeAtomicAdd(&stats[768 + col], q_acc);
            }
        }
    }
}

// ---------------- BN+ReLU transform for head A staging ----------------
__device__ __forceinline__ uint4 bn_relu_pack(uint4 w, const float* __restrict__ sc,
                                              const float* __restrict__ sh, int c)
{
    float4 sc0 = *(const float4*)(sc + c), sc1 = *(const float4*)(sc + c + 4);
    float4 sh0 = *(const float4*)(sh + c), sh1 = *(const float4*)(sh + c + 4);
    uint4 o;
    o.x = pack2(fmaxf(b2f_lo(w.x) * sc0.x + sh0.x, 0.f), fmaxf(b2f_hi(w.x) * sc0.y + sh0.y, 0.f));
    o.y = pack2(fmaxf(b2f_lo(w.y) * sc0.z + sh0.z, 0.f), fmaxf(b2f_hi(w.y) * sc0.w + sh0.w, 0.f));
    o.z = pack2(fmaxf(b2f_lo(w.z) * sc1.x + sh1.x, 0.f), fmaxf(b2f_hi(w.z) * sc1.y + sh1.y, 0.f));
    o.w = pack2(fmaxf(b2f_lo(w.w) * sc1.z + sh1.z, 0.f), fmaxf(b2f_hi(w.w) * sc1.w + sh1.w, 0.f));
    return o;
}

// ---------------- head GEMM, 2-phase: BN+ReLU fused A reg-staging, B via global_load_lds ----------------
__global__ __launch_bounds__(256) void mm_gemm_bn(
    const ushort* __restrict__ A, const ushort* __restrict__ Bt,
    const float* __restrict__ bias,
    const float* __restrict__ sc, const float* __restrict__ sh,
    ushort* __restrict__ Cb, int ldc, int M)
{
    const int K = 768, lda = 768;
    __shared__ ushort lds[16384];
    const int tid = threadIdx.x;
    const int wave = tid >> 6, lane = tid & 63;
    const int row0 = blockIdx.x * 128;
    const int col0 = blockIdx.y * 128;

    int arow0 = min(row0 + wave * 16 + (lane >> 2), M - 1);
    int arow1 = min(row0 + 64 + wave * 16 + (lane >> 2), M - 1);
    int brow0 = col0 + wave * 16 + (lane >> 2);
    int brow1 = col0 + 64 + wave * 16 + (lane >> 2);
    const ushort* pa0 = A + (size_t)arow0 * lda + (lane & 3) * 8;
    const ushort* pa1 = A + (size_t)arow1 * lda + (lane & 3) * 8;
    const ushort* pb0 = Bt + (size_t)brow0 * K + (lane & 3) * 8;
    const ushort* pb1 = Bt + (size_t)brow1 * K + (lane & 3) * 8;
    const int wr = (wave >> 1) * 64, wc = (wave & 1) * 64;

    f32x4 zero = {0.f, 0.f, 0.f, 0.f};
    f32x4 acc[4][4];
    #pragma unroll
    for (int m = 0; m < 4; ++m)
        #pragma unroll
        for (int n = 0; n < 4; ++n) acc[m][n] = zero;

    const int nt = K >> 5;   // 24

#define STAGE_B(bufi) { \
    ushort* Lb = lds + (bufi) * 8192; \
    __builtin_amdgcn_global_load_lds((const __attribute__((address_space(1))) void*)pb0, \
        (__attribute__((address_space(3))) void*)(Lb + 4096 + wave * 512), 16, 0, 0); \
    __builtin_amdgcn_global_load_lds((const __attribute__((address_space(1))) void*)pb1, \
        (__attribute__((address_space(3))) void*)(Lb + 6144 + wave * 512), 16, 0, 0); \
    pb0 += 32; pb1 += 32; }

    // prologue: tile 0
    {
        STAGE_B(0);
        uint4 w0 = *(const uint4*)pa0; uint4 w1 = *(const uint4*)pa1;
        pa0 += 32; pa1 += 32;
        int c = (lane & 3) * 8;
        uint4 oa = bn_relu_pack(w0, sc, sh, c);
        uint4 ob = bn_relu_pack(w1, sc, sh, c);
        *(uint4*)(lds + wave * 512 + lane * 8) = oa;
        *(uint4*)(lds + 2048 + wave * 512 + lane * 8) = ob;
    }
    __syncthreads();

    for (int t = 0; t < nt; ++t) {
        int cur = t & 1;
        uint4 w0n, w1n; int cn = 0;
        bool more = (t + 1 < nt);
        if (more) {
            STAGE_B(cur ^ 1);
            w0n = *(const uint4*)pa0; w1n = *(const uint4*)pa1;
            pa0 += 32; pa1 += 32;
            cn = (t + 1) * 32 + (lane & 3) * 8;
        }
        const ushort* As = lds + cur * 8192;
        const ushort* Bs = As + 4096;
        short8 a[4], b[4];
        #pragma unroll
        for (int m = 0; m < 4; ++m)
            a[m] = *(const short8*)&As[(wr + m * 16 + (lane & 15)) * 32 + (lane >> 4) * 8];
        #pragma unroll
        for (int n = 0; n < 4; ++n)
            b[n] = *(const short8*)&Bs[(wc + n * 16 + (lane & 15)) * 32 + (lane >> 4) * 8];
        #pragma unroll
        for (int m = 0; m < 4; ++m)
            #pragma unroll
            for (int n = 0; n < 4; ++n)
                acc[m][n] = __builtin_amdgcn_mfma_f32_16x16x32_bf16(a[m], b[n], acc[m][n], 0, 0, 0);
        if (more) {
            ushort* Ln = lds + (cur ^ 1) * 8192;
            uint4 oa = bn_relu_pack(w0n, sc, sh, cn);
            uint4 ob = bn_relu_pack(w1n, sc, sh, cn);
            *(uint4*)(Ln + wave * 512 + lane * 8) = oa;
            *(uint4*)(Ln + 2048 + wave * 512 + lane * 8) = ob;
            __syncthreads();
        }
    }
#undef STAGE_B

    #pragma unroll
    for (int n = 0; n < 4; ++n) {
        int col = col0 + wc + n * 16 + (lane & 15);
        float bb = bias[col];
        #pragma unroll
        for (int m = 0; m < 4; ++m) {
            int rb = row0 + wr + m * 16 + (lane >> 4) * 4;
            #pragma unroll
            for (int r = 0; r < 4; ++r) {
                int row = rb + r;
                if (row < M)
                    Cb[(size_t)row * ldc + col] = f2b(fmaxf(acc[m][n][r] + bb, 0.f));
            }
        }
    }
}

__global__ void mm_bn_fin(const float* __restrict__ sums, const float* __restrict__ gamma,
                          const float* __restrict__ beta,
                          float* __restrict__ scale, float* __restrict__ shift)
{
    int c = blockIdx.x * 256 + threadIdx.x;
    if (c >= 768) return;
    float inv = 1.f / (float)NN;
    float mu = sums[c] * inv;
    float ex2 = sums[768 + c] * inv;
    float var = fmaxf(ex2 - mu * mu, 0.f);
    float rs = rsqrtf(var + 1e-5f);
    float sc = gamma[c] * rs;
    scale[c] = sc;
    shift[c] = beta[c] - mu * sc;
}

// ---------------- out = h2 @ W2 + b2 (h2 bf16 [NN,256], W2 fp32 [256,40]) ----------------
__global__ __launch_bounds__(256) void mm_head2(const ushort* __restrict__ h2b, const float* __restrict__ W2,
                                                const float* __restrict__ b2, float* __restrict__ out)
{
    __shared__ float Ws[256 * 40];
    for (int i = threadIdx.x; i < 256 * 40; i += 256) Ws[i] = W2[i];
    __syncthreads();
    int row = blockIdx.x * 32 + (threadIdx.x >> 3);
    int cg = (threadIdx.x & 7) * 5;
    if (row >= NN) return;
    const ushort* hr = h2b + (size_t)row * 256;
    float acc[5] = {0, 0, 0, 0, 0};
    for (int k = 0; k < 256; k += 8) {
        uint4 w = *(const uint4*)(hr + k);
        float a0 = b2f_lo(w.x), a1 = b2f_hi(w.x), a2 = b2f_lo(w.y), a3 = b2f_hi(w.y);
        float a4 = b2f_lo(w.z), a5 = b2f_hi(w.z), a6 = b2f_lo(w.w), a7 = b2f_hi(w.w);
        #pragma unroll
        for (int j = 0; j < 5; ++j) {
            acc[j] += a0 * Ws[(k + 0) * 40 + cg + j] + a1 * Ws[(k + 1) * 40 + cg + j]
                    + a2 * Ws[(k + 2) * 40 + cg + j] + a3 * Ws[(k + 3) * 40 + cg + j]
                    + a4 * Ws[(k + 4) * 40 + cg + j] + a5 * Ws[(k + 5) * 40 + cg + j]
                    + a6 * Ws[(k + 6) * 40 + cg + j] + a7 * Ws[(k + 7) * 40 + cg + j];
        }
    }
    #pragma unroll
    for (int j = 0; j < 5; ++j) out[(size_t)row * 40 + cg + j] = acc[j] + b2[cg + j];
}

extern "C" void kernel_launch(void* const* d_in, const int* in_sizes, int n_in,
                              void* d_out, int out_size, void* d_ws, size_t ws_size,
                              hipStream_t stream)
{
    const float* x      = (const float*)d_in[0];
    const int*   ei     = (const int*)d_in[1];
    const float* W_gat  = (const float*)d_in[2];
    const float* att_s  = (const float*)d_in[3];
    const float* att_d  = (const float*)d_in[4];
    const float* b_gat  = (const float*)d_in[5];
    const float* W_gin1 = (const float*)d_in[6];
    const float* b_gin1 = (const float*)d_in[7];
    const float* W_gin2 = (const float*)d_in[8];
    const float* b_gin2 = (const float*)d_in[9];
    const float* W_gcn  = (const float*)d_in[10];
    const float* b_gcn  = (const float*)d_in[11];
    const float* gamma  = (const float*)d_in[12];
    const float* beta   = (const float*)d_in[13];
    const float* W_lin  = (const float*)d_in[14];
    const float* b_lin  = (const float*)d_in[15];
    const float* W_lin2 = (const float*)d_in[16];
    const float* b_lin2 = (const float*)d_in[17];
    const int* src = ei;
    const int* dst = ei + NE;
    float* out = (float*)d_out;

    float* ws = (float*)d_ws;
    size_t off = 0;
    ushort* xb      = (ushort*)(ws + off); off += (size_t)NN * 64;    // [NN][128] bf16
    ushort* aggb    = (ushort*)(ws + off); off += (size_t)NN * 192;   // [NN][384] bf16: gat|gin|gcn
    ushort* hid_b   = (ushort*)(ws + off); off += (size_t)NN * 128;   // GIN hidden; later h2
    ushort* xcb     = (ushort*)(ws + off); off += (size_t)NN * 384;   // [NN][768] bf16
    float* es       = ws + off; off += NN;
    float* ed       = ws + off; off += NN;
    float* dis      = ws + off; off += NN;
    float* va       = ws + off; off += 128;
    float* vd       = ws + off; off += 128;
    float* bnsum    = ws + off; off += 1536;
    float* bscale   = ws + off; off += 768;
    float* bshift   = ws + off; off += 768;
    ushort* wt_gat  = (ushort*)(ws + off); off += 128 * 256 / 2;
    ushort* wt_gin1 = (ushort*)(ws + off); off += 128 * 256 / 2;
    ushort* wt_gin2 = (ushort*)(ws + off); off += 256 * 256 / 2;
    ushort* wt_gcn  = (ushort*)(ws + off); off += 128 * 256 / 2;
    ushort* wt_lin  = (ushort*)(ws + off); off += 768 * 256 / 2;
    int* part       = (int*)(ws + off); off += 256;
    int* row_ptr    = (int*)(ws + off); off += NN + 1;
    int* cursor     = (int*)(ws + off); off += NN;
    int* csr_src    = (int*)(ws + off); off += NE;

    dim3 blk(256);
    dim3 gemm_grid((NN + 127) / 128, 2);   // N=256 -> 2 col blocks
    const int NB = (NN + 255) / 256;       // scan tiles

    // ---- zero accumulators early ----
    hipMemsetAsync(bnsum, 0, 1536 * sizeof(float), stream);
    hipMemsetAsync(cursor, 0, NN * sizeof(int), stream);

    // ---- weight transposes / attention vectors ----
    mm_wt<<<(128 * 256 + 255) / 256, blk, 0, stream>>>(W_gat, wt_gat, 128, 256);
    mm_wt<<<(128 * 256 + 255) / 256, blk, 0, stream>>>(W_gin1, wt_gin1, 128, 256);
    mm_wt<<<(256 * 256 + 255) / 256, blk, 0, stream>>>(W_gin2, wt_gin2, 256, 256);
    mm_wt<<<(128 * 256 + 255) / 256, blk, 0, stream>>>(W_gcn, wt_gcn, 128, 256);
    mm_wt<<<(768 * 256 + 255) / 256, blk, 0, stream>>>(W_lin, wt_lin, 768, 256);
    mm_attvec<<<1, blk, 0, stream>>>(W_gat, att_s, att_d, va, vd);

    // ---- fused convert + attention dots ----
    mm_cvt_es<<<(NN + 3) / 4, blk, 0, stream>>>(x, va, vd, xb, es, ed);

    // ---- CSR build ----
    mm_count<<<(NE + 255) / 256, blk, 0, stream>>>(dst, cursor);
    mm_scan1<<<NB, blk, 0, stream>>>(cursor, part);
    mm_scan2<<<1, blk, 0, stream>>>(part, NB);
    mm_scan3<<<NB, blk, 0, stream>>>(cursor, part, row_ptr, cursor);
    mm_dis<<<(NN + 255) / 256, blk, 0, stream>>>(row_ptr, dis);
    mm_fill<<<(NE + 255) / 256, blk, 0, stream>>>(src, dst, cursor, csr_src);

    // ---- fused per-node softmax + 3-way gather ----
    mm_node_agg<<<(NN + 3) / 4, blk, 0, stream>>>(row_ptr, csr_src, es, ed, dis, xb, aggb);

    // ---- GEMMs (branch GEMMs accumulate BN stats in epilogue) ----
    mm_gemm_bf<<<gemm_grid, blk, 0, stream>>>(aggb,       384, wt_gat,  b_gat,  bnsum,       xcb,       768, NN, 128, 0);
    mm_gemm_bf<<<gemm_grid, blk, 0, stream>>>(aggb + 128, 384, wt_gin1, b_gin1, nullptr,     hid_b,     256, NN, 128, 1);
    mm_gemm_bf<<<gemm_grid, blk, 0, stream>>>(hid_b,      256, wt_gin2, b_gin2, bnsum + 256, xcb + 256, 768, NN, 256, 0);
    mm_gemm_bf<<<gemm_grid, blk, 0, stream>>>(aggb + 256, 384, wt_gcn,  b_gcn,  bnsum + 512, xcb + 512, 768, NN, 128, 0);

    // ---- BN scale/shift ----
    mm_bn_fin<<<3, blk, 0, stream>>>(bnsum, gamma, beta, bscale, bshift);

    // ---- head: BN+ReLU fused into A staging (2-phase) ----
    mm_gemm_bn<<<gemm_grid, blk, 0, stream>>>(xcb, wt_lin, b_lin, bscale, bshift, hid_b, 256, NN);
    mm_head2<<<(NN + 31) / 32, blk, 0, stream>>>(hid_b, W_lin2, b_lin2, out);
}

// Round 7
// 377.073 us; speedup vs baseline: 13.3633x; 1.1116x over previous
//
#include <hip/hip_runtime.h>
#include <math.h>

#define NN 50000
#define NE 500000
// D_IN=128, D_H=256, D_C=768, D_OUT=40

typedef __attribute__((ext_vector_type(8))) short short8;   // 8 bf16 (4 VGPRs)
typedef __attribute__((ext_vector_type(4))) float f32x4;    // MFMA acc

__device__ __forceinline__ float leaky02(float x) { return x > 0.f ? x : 0.2f * x; }
__device__ __forceinline__ ushort f2b(float f) {
    uint u = __float_as_uint(f);
    u += 0x7fffu + ((u >> 16) & 1u);          // RNE
    return (ushort)(u >> 16);
}
__device__ __forceinline__ float b2f(ushort h) { return __uint_as_float(((uint)h) << 16); }
__device__ __forceinline__ float b2f_lo(uint w) { return __uint_as_float(w << 16); }
__device__ __forceinline__ float b2f_hi(uint w) { return __uint_as_float(w & 0xffff0000u); }
__device__ __forceinline__ uint pack2(float a, float b) {
    return (uint)f2b(a) | ((uint)f2b(b) << 16);
}

// ---------------- W [K][Nc] fp32 -> Wt [Nc][K] bf16 ----------------
__global__ void mm_wt(const float* __restrict__ W, ushort* __restrict__ Wt, int K, int Nc)
{
    int idx = blockIdx.x * 256 + threadIdx.x;
    if (idx >= K * Nc) return;
    int n = idx / K, k = idx - n * K;
    Wt[idx] = f2b(W[(size_t)k * Nc + n]);
}

// ---------------- va = W_gat @ att_src, vd = W_gat @ att_dst (both [128]) ----------------
__global__ void mm_attvec(const float* __restrict__ W, const float* __restrict__ as_,
                          const float* __restrict__ ad_, float* __restrict__ va, float* __restrict__ vd)
{
    int i = threadIdx.x;           // 0..255
    const float* vec = (i < 128) ? as_ : ad_;
    int k = i & 127;
    float s = 0.f;
    for (int j = 0; j < 256; ++j) s += W[(size_t)k * 256 + j] * vec[j];
    if (i < 128) va[k] = s; else vd[k] = s;
}

// ---------------- fused: x fp32 -> xb bf16, es/ed = x.va / x.vd (wave per node) ----------------
__global__ __launch_bounds__(256) void mm_cvt_es(const float* __restrict__ x,
                                                 const float* __restrict__ va, const float* __restrict__ vd,
                                                 ushort* __restrict__ xb,
                                                 float* __restrict__ es, float* __restrict__ ed)
{
    int node = blockIdx.x * 4 + (threadIdx.x >> 6);
    int lane = threadIdx.x & 63;
    if (node >= NN) return;
    float2 xv = *(const float2*)(x + (size_t)node * 128 + lane * 2);
    float2 a = *(const float2*)(va + lane * 2);
    float2 b = *(const float2*)(vd + lane * 2);
    *(uint*)(xb + (size_t)node * 128 + lane * 2) = pack2(xv.x, xv.y);
    float s = xv.x * a.x + xv.y * a.y;
    float d = xv.x * b.x + xv.y * b.y;
    #pragma unroll
    for (int off = 32; off; off >>= 1) {
        s += __shfl_down(s, off);
        d += __shfl_down(d, off);
    }
    if (lane == 0) { es[node] = s; ed[node] = d; }
}

// ---------------- CSR build: count -> 3-phase scan -> fill ----------------
__global__ void mm_count(const int* __restrict__ dst, int* __restrict__ deg)
{
    int e = blockIdx.x * 256 + threadIdx.x;
    if (e >= NE) return;
    atomicAdd(&deg[dst[e]], 1);
}

__global__ __launch_bounds__(256) void mm_scan1(const int* __restrict__ deg, int* __restrict__ part)
{
    __shared__ int red[256];
    int i = blockIdx.x * 256 + threadIdx.x;
    red[threadIdx.x] = (i < NN) ? deg[i] : 0;
    __syncthreads();
    for (int off = 128; off; off >>= 1) {
        if (threadIdx.x < off) red[threadIdx.x] += red[threadIdx.x + off];
        __syncthreads();
    }
    if (threadIdx.x == 0) part[blockIdx.x] = red[0];
}

__global__ __launch_bounds__(256) void mm_scan2(int* __restrict__ part, int nb)
{
    __shared__ int tile[256];
    int t = threadIdx.x;
    int v = (t < nb) ? part[t] : 0;
    tile[t] = v; __syncthreads();
    for (int off = 1; off < 256; off <<= 1) {
        int a = (t >= off) ? tile[t - off] : 0;
        __syncthreads();
        tile[t] += a;
        __syncthreads();
    }
    if (t < nb) part[t] = tile[t] - v;   // exclusive
}

__global__ __launch_bounds__(256) void mm_scan3(const int* __restrict__ deg, const int* __restrict__ part,
                                                int* __restrict__ row_ptr, int* __restrict__ cursor)
{
    __shared__ int tile[256];
    int t = threadIdx.x;
    int i = blockIdx.x * 256 + t;
    int v = (i < NN) ? deg[i] : 0;
    tile[t] = v; __syncthreads();
    for (int off = 1; off < 256; off <<= 1) {
        int a = (t >= off) ? tile[t - off] : 0;
        __syncthreads();
        tile[t] += a;
        __syncthreads();
    }
    if (i < NN) {
        int ex = part[blockIdx.x] + tile[t] - v;
        row_ptr[i] = ex;
        cursor[i] = ex;
    }
    if (i == 0) row_ptr[NN] = NE;
}

__global__ void mm_fill(const int* __restrict__ src, const int* __restrict__ dst,
                        int* __restrict__ cursor, int* __restrict__ csr_src)
{
    int e = blockIdx.x * 256 + threadIdx.x;
    if (e >= NE) return;
    int pos = atomicAdd(&cursor[dst[e]], 1);
    csr_src[pos] = src[e];
}

__global__ void mm_dis(const int* __restrict__ row_ptr, float* __restrict__ dis)
{
    int i = blockIdx.x * 256 + threadIdx.x;
    if (i >= NN) return;
    dis[i] = rsqrtf((float)(row_ptr[i + 1] - row_ptr[i] + 1));
}

// ---------------- fused per-node: GAT softmax (in-reg) + GAT/GIN/GCN gather, wave per node ----------------
__global__ __launch_bounds__(256) void mm_node_agg(
    const int* __restrict__ row_ptr, const int* __restrict__ csr_src,
    const float* __restrict__ es, const float* __restrict__ ed,
    const float* __restrict__ dis,
    const ushort* __restrict__ xb, ushort* __restrict__ aggb)
{
    int d = blockIdx.x * 4 + (threadIdx.x >> 6);
    int lane = threadIdx.x & 63;
    if (d >= NN) return;
    int start = row_ptr[d], end = row_ptr[d + 1];
    float edd = ed[d], disd = dis[d];
    float selfv = leaky02(es[d] + edd);

    int myidx = -1; float myl = -3.0e38f, mynw = 0.f;
    if (start + lane < end) {
        myidx = csr_src[start + lane];
        myl = leaky02(es[myidx] + edd);
        mynw = dis[myidx] * disd;
    }
    float lmax = fmaxf(selfv, myl);
    for (int e = start + 64 + lane; e < end; e += 64)
        lmax = fmaxf(lmax, leaky02(es[csr_src[e]] + edd));
    #pragma unroll
    for (int off = 1; off < 64; off <<= 1) lmax = fmaxf(lmax, __shfl_xor(lmax, off));
    float m = lmax;

    float lsum = (myidx >= 0) ? __expf(myl - m) : 0.f;
    if (lane == 0) lsum += __expf(selfv - m);
    for (int e = start + 64 + lane; e < end; e += 64)
        lsum += __expf(leaky02(es[csr_src[e]] + edd) - m);
    #pragma unroll
    for (int off = 1; off < 64; off <<= 1) lsum += __shfl_xor(lsum, off);
    float inv = 1.f / lsum;
    float myal = __expf(myl - m) * inv;

    float aself = __expf(selfv - m) * inv;
    float d2 = disd * disd;
    uint wself = *(const uint*)(xb + (size_t)d * 128 + lane * 2);
    float x0 = b2f_lo(wself), x1 = b2f_hi(wself);
    float gat0 = aself * x0, gat1 = aself * x1;
    float gin0 = x0, gin1 = x1;
    float gcn0 = d2 * x0, gcn1 = d2 * x1;

    for (int base = start; base < end; base += 64) {
        int cnt = min(64, end - base);
        int bidx; float bal, bnw;
        if (base == start) { bidx = myidx; bal = myal; bnw = mynw; }
        else {
            bidx = -1; bal = 0.f; bnw = 0.f;
            if (base + lane < end) {
                bidx = csr_src[base + lane];
                bal = __expf(leaky02(es[bidx] + edd) - m) * inv;
                bnw = dis[bidx] * disd;
            }
        }
        int j = 0;
        for (; j + 4 <= cnt; j += 4) {
            int   s0 = __shfl(bidx, j),     s1 = __shfl(bidx, j + 1);
            int   s2 = __shfl(bidx, j + 2), s3 = __shfl(bidx, j + 3);
            float a0 = __shfl(bal, j),      a1 = __shfl(bal, j + 1);
            float a2 = __shfl(bal, j + 2),  a3 = __shfl(bal, j + 3);
            float n0 = __shfl(bnw, j),      n1 = __shfl(bnw, j + 1);
            float n2 = __shfl(bnw, j + 2),  n3 = __shfl(bnw, j + 3);
            uint w0 = *(const uint*)(xb + (size_t)s0 * 128 + lane * 2);
            uint w1 = *(const uint*)(xb + (size_t)s1 * 128 + lane * 2);
            uint w2 = *(const uint*)(xb + (size_t)s2 * 128 + lane * 2);
            uint w3 = *(const uint*)(xb + (size_t)s3 * 128 + lane * 2);
            float p0, p1;
            p0 = b2f_lo(w0); p1 = b2f_hi(w0);
            gat0 += a0 * p0; gat1 += a0 * p1; gin0 += p0; gin1 += p1; gcn0 += n0 * p0; gcn1 += n0 * p1;
            p0 = b2f_lo(w1); p1 = b2f_hi(w1);
            gat0 += a1 * p0; gat1 += a1 * p1; gin0 += p0; gin1 += p1; gcn0 += n1 * p0; gcn1 += n1 * p1;
            p0 = b2f_lo(w2); p1 = b2f_hi(w2);
            gat0 += a2 * p0; gat1 += a2 * p1; gin0 += p0; gin1 += p1; gcn0 += n2 * p0; gcn1 += n2 * p1;
            p0 = b2f_lo(w3); p1 = b2f_hi(w3);
            gat0 += a3 * p0; gat1 += a3 * p1; gin0 += p0; gin1 += p1; gcn0 += n3 * p0; gcn1 += n3 * p1;
        }
        for (; j < cnt; ++j) {
            int   s0 = __shfl(bidx, j);
            float a0 = __shfl(bal, j);
            float n0 = __shfl(bnw, j);
            uint w0 = *(const uint*)(xb + (size_t)s0 * 128 + lane * 2);
            float p0 = b2f_lo(w0), p1 = b2f_hi(w0);
            gat0 += a0 * p0; gat1 += a0 * p1; gin0 += p0; gin1 += p1; gcn0 += n0 * p0; gcn1 += n0 * p1;
        }
    }
    ushort* orow = aggb + (size_t)d * 384;
    *(uint*)(orow + lane * 2)       = pack2(gat0, gat1);
    *(uint*)(orow + 128 + lane * 2) = pack2(gin0, gin1);
    *(uint*)(orow + 256 + lane * 2) = pack2(gcn0, gcn1);
}

// ---------------- pipelined bf16 MFMA GEMM core: counted vmcnt, 2 buffers, 2 raw barriers ----------------
// Cb = op(A @ Bt^T + bias); optional per-column sum/sumsq into stats[col], stats[768+col].
__device__ __forceinline__ void gemm_core(
    const ushort* __restrict__ A, int lda, const ushort* __restrict__ Bt,
    const float* __restrict__ bias, float* __restrict__ stats,
    ushort* __restrict__ Cb, int ldc, int M, int K, int relu,
    ushort* lds)
{
    const int tid = threadIdx.x;
    const int wave = tid >> 6, lane = tid & 63;
    const int row0 = blockIdx.x * 128;
    const int col0 = blockIdx.y * 128;

    int arow0 = min(row0 + wave * 16 + (lane >> 2), M - 1);
    int arow1 = min(row0 + 64 + wave * 16 + (lane >> 2), M - 1);
    int brow0 = col0 + wave * 16 + (lane >> 2);
    int brow1 = col0 + 64 + wave * 16 + (lane >> 2);
    const ushort* pa0 = A + (size_t)arow0 * lda + (lane & 3) * 8;
    const ushort* pa1 = A + (size_t)arow1 * lda + (lane & 3) * 8;
    const ushort* pb0 = Bt + (size_t)brow0 * K + (lane & 3) * 8;
    const ushort* pb1 = Bt + (size_t)brow1 * K + (lane & 3) * 8;
    const int wr = (wave >> 1) * 64, wc = (wave & 1) * 64;

    f32x4 zero = {0.f, 0.f, 0.f, 0.f};
    f32x4 acc[4][4];
    #pragma unroll
    for (int m = 0; m < 4; ++m)
        #pragma unroll
        for (int n = 0; n < 4; ++n) acc[m][n] = zero;

    const int nt = K >> 5;

#define STAGE_C(bufi) { \
    ushort* Lb = lds + (bufi) * 8192; \
    __builtin_amdgcn_global_load_lds((const __attribute__((address_space(1))) void*)pa0, \
        (__attribute__((address_space(3))) void*)(Lb + wave * 512), 16, 0, 0); \
    __builtin_amdgcn_global_load_lds((const __attribute__((address_space(1))) void*)pa1, \
        (__attribute__((address_space(3))) void*)(Lb + 2048 + wave * 512), 16, 0, 0); \
    __builtin_amdgcn_global_load_lds((const __attribute__((address_space(1))) void*)pb0, \
        (__attribute__((address_space(3))) void*)(Lb + 4096 + wave * 512), 16, 0, 0); \
    __builtin_amdgcn_global_load_lds((const __attribute__((address_space(1))) void*)pb1, \
        (__attribute__((address_space(3))) void*)(Lb + 6144 + wave * 512), 16, 0, 0); \
    pa0 += 32; pa1 += 32; pb0 += 32; pb1 += 32; }

    STAGE_C(0);
    for (int t = 0; t < nt; ++t) {
        int cur = t & 1;
        if (t + 1 < nt) {
            STAGE_C(cur ^ 1);
            // wait only for buf-cur's 4 loads; buf-next's 4 stay in flight
            asm volatile("s_waitcnt vmcnt(4) lgkmcnt(0)" ::: "memory");
        } else {
            asm volatile("s_waitcnt vmcnt(0) lgkmcnt(0)" ::: "memory");
        }
        __builtin_amdgcn_s_barrier();
        const ushort* As = lds + cur * 8192;
        const ushort* Bs = As + 4096;
        short8 a[4], b[4];
        #pragma unroll
        for (int m = 0; m < 4; ++m)
            a[m] = *(const short8*)&As[(wr + m * 16 + (lane & 15)) * 32 + (lane >> 4) * 8];
        #pragma unroll
        for (int n = 0; n < 4; ++n)
            b[n] = *(const short8*)&Bs[(wc + n * 16 + (lane & 15)) * 32 + (lane >> 4) * 8];
        #pragma unroll
        for (int m = 0; m < 4; ++m)
            #pragma unroll
            for (int n = 0; n < 4; ++n)
                acc[m][n] = __builtin_amdgcn_mfma_f32_16x16x32_bf16(a[m], b[n], acc[m][n], 0, 0, 0);
        if (t + 1 < nt) __builtin_amdgcn_s_barrier();   // protect buf cur from next iter's STAGE
    }
#undef STAGE_C

    #pragma unroll
    for (int n = 0; n < 4; ++n) {
        int col = col0 + wc + n * 16 + (lane & 15);   // local col 0..255
        float bb = bias ? bias[col] : 0.f;
        float s_acc = 0.f, q_acc = 0.f;
        #pragma unroll
        for (int m = 0; m < 4; ++m) {
            int rb = row0 + wr + m * 16 + (lane >> 4) * 4;
            #pragma unroll
            for (int r = 0; r < 4; ++r) {
                int row = rb + r;
                if (row < M) {
                    float v = acc[m][n][r] + bb;
                    if (relu) v = fmaxf(v, 0.f);
                    Cb[(size_t)row * ldc + col] = f2b(v);
                    s_acc += v; q_acc += v * v;
                }
            }
        }
        if (stats) {
            s_acc += __shfl_xor(s_acc, 16); q_acc += __shfl_xor(q_acc, 16);
            s_acc += __shfl_xor(s_acc, 32); q_acc += __shfl_xor(q_acc, 32);
            if (lane < 16) {
                unsafeAtomicAdd(&stats[col], s_acc);
                unsafeAtomicAdd(&stats[768 + col], q_acc);
            }
        }
    }
}

// ---------------- z-batched branch GEMMs: z=0 GAT, z=1 GIN1, z=2 GCN (all K=128, lda=384) ----------------
__global__ __launch_bounds__(256) void mm_gemm3(
    const ushort* __restrict__ aggb,
    const ushort* __restrict__ wt_gat, const ushort* __restrict__ wt_gin1, const ushort* __restrict__ wt_gcn,
    const float* __restrict__ b_gat, const float* __restrict__ b_gin1, const float* __restrict__ b_gcn,
    float* __restrict__ bnsum,
    ushort* __restrict__ xcb, ushort* __restrict__ hid_b)
{
    __shared__ ushort lds[16384];
    const ushort* A; const ushort* Bt; const float* bias; float* stats; ushort* Cb; int ldc; int relu;
    if (blockIdx.z == 0)      { A = aggb;       Bt = wt_gat;  bias = b_gat;  stats = bnsum;       Cb = xcb;       ldc = 768; relu = 0; }
    else if (blockIdx.z == 1) { A = aggb + 128; Bt = wt_gin1; bias = b_gin1; stats = nullptr;     Cb = hid_b;     ldc = 256; relu = 1; }
    else                      { A = aggb + 256; Bt = wt_gcn;  bias = b_gcn;  stats = bnsum + 512; Cb = xcb + 512; ldc = 768; relu = 0; }
    gemm_core(A, 384, Bt, bias, stats, Cb, ldc, NN, 128, relu, lds);
}

// ---------------- generic pipelined GEMM (gin2: K=256) ----------------
__global__ __launch_bounds__(256) void mm_gemm_bf(
    const ushort* __restrict__ A, int lda, const ushort* __restrict__ Bt,
    const float* __restrict__ bias, float* __restrict__ stats,
    ushort* __restrict__ Cb, int ldc, int M, int K, int relu)
{
    __shared__ ushort lds[16384];
    gemm_core(A, lda, Bt, bias, stats, Cb, ldc, M, K, relu, lds);
}

// ---------------- BN+ReLU transform (sc/sh from LDS) ----------------
__device__ __forceinline__ uint4 bn_relu_pack_l(uint4 w, const float* sc, const float* sh, int c)
{
    uint4 o;
    o.x = pack2(fmaxf(b2f_lo(w.x) * sc[c + 0] + sh[c + 0], 0.f), fmaxf(b2f_hi(w.x) * sc[c + 1] + sh[c + 1], 0.f));
    o.y = pack2(fmaxf(b2f_lo(w.y) * sc[c + 2] + sh[c + 2], 0.f), fmaxf(b2f_hi(w.y) * sc[c + 3] + sh[c + 3], 0.f));
    o.z = pack2(fmaxf(b2f_lo(w.z) * sc[c + 4] + sh[c + 4], 0.f), fmaxf(b2f_hi(w.z) * sc[c + 5] + sh[c + 5], 0.f));
    o.w = pack2(fmaxf(b2f_lo(w.w) * sc[c + 6] + sh[c + 6], 0.f), fmaxf(b2f_hi(w.w) * sc[c + 7] + sh[c + 7], 0.f));
    return o;
}

// ---------------- head GEMM, pipelined: BN+ReLU fused A reg-staging, B via global_load_lds ----------------
__global__ __launch_bounds__(256) void mm_gemm_bn(
    const ushort* __restrict__ A, const ushort* __restrict__ Bt,
    const float* __restrict__ bias,
    const float* __restrict__ sc, const float* __restrict__ sh,
    ushort* __restrict__ Cb, int ldc, int M)
{
    const int K = 768, lda = 768;
    __shared__ ushort lds[16384];
    __shared__ float sc_l[768], sh_l[768];
    const int tid = threadIdx.x;
    for (int i = tid; i < 768; i += 256) { sc_l[i] = sc[i]; sh_l[i] = sh[i]; }

    const int wave = tid >> 6, lane = tid & 63;
    const int row0 = blockIdx.x * 128;
    const int col0 = blockIdx.y * 128;

    int arow0 = min(row0 + wave * 16 + (lane >> 2), M - 1);
    int arow1 = min(row0 + 64 + wave * 16 + (lane >> 2), M - 1);
    int brow0 = col0 + wave * 16 + (lane >> 2);
    int brow1 = col0 + 64 + wave * 16 + (lane >> 2);
    const ushort* pa0 = A + (size_t)arow0 * lda + (lane & 3) * 8;
    const ushort* pa1 = A + (size_t)arow1 * lda + (lane & 3) * 8;
    const ushort* pb0 = Bt + (size_t)brow0 * K + (lane & 3) * 8;
    const ushort* pb1 = Bt + (size_t)brow1 * K + (lane & 3) * 8;
    const int wr = (wave >> 1) * 64, wc = (wave & 1) * 64;

    f32x4 zero = {0.f, 0.f, 0.f, 0.f};
    f32x4 acc[4][4];
    #pragma unroll
    for (int m = 0; m < 4; ++m)
        #pragma unroll
        for (int n = 0; n < 4; ++n) acc[m][n] = zero;

    const int nt = K >> 5;   // 24

#define STAGE_B(bufi) { \
    ushort* Lb = lds + (bufi) * 8192; \
    __builtin_amdgcn_global_load_lds((const __attribute__((address_space(1))) void*)pb0, \
        (__attribute__((address_space(3))) void*)(Lb + 4096 + wave * 512), 16, 0, 0); \
    __builtin_amdgcn_global_load_lds((const __attribute__((address_space(1))) void*)pb1, \
        (__attribute__((address_space(3))) void*)(Lb + 6144 + wave * 512), 16, 0, 0); \
    pb0 += 32; pb1 += 32; }

    // prologue: tile 0 (full drain once; also covers sc_l/sh_l staging)
    uint4 w0 = *(const uint4*)pa0, w1 = *(const uint4*)pa1;
    pa0 += 32; pa1 += 32;
    STAGE_B(0);
    __syncthreads();
    {
        int c = (lane & 3) * 8;
        *(uint4*)(lds + wave * 512 + lane * 8) = bn_relu_pack_l(w0, sc_l, sh_l, c);
        *(uint4*)(lds + 2048 + wave * 512 + lane * 8) = bn_relu_pack_l(w1, sc_l, sh_l, c);
    }

    for (int t = 0; t < nt; ++t) {
        int cur = t & 1;
        bool more = (t + 1 < nt);
        uint4 w0n, w1n;
        if (more) {
            w0n = *(const uint4*)pa0; w1n = *(const uint4*)pa1;   // A-reg loads FIRST (oldest)
            pa0 += 32; pa1 += 32;
            STAGE_B(cur ^ 1);                                     // then 2 gload_lds
            // outstanding newest 4 = {w0n,w1n,gl,gl}; wait drains buf-cur's B loads + own ds_writes
            asm volatile("s_waitcnt vmcnt(4) lgkmcnt(0)" ::: "memory");
        } else {
            asm volatile("s_waitcnt vmcnt(0) lgkmcnt(0)" ::: "memory");
        }
        __builtin_amdgcn_s_barrier();
        const ushort* As = lds + cur * 8192;
        const ushort* Bs = As + 4096;
        short8 a[4], b[4];
        #pragma unroll
        for (int m = 0; m < 4; ++m)
            a[m] = *(const short8*)&As[(wr + m * 16 + (lane & 15)) * 32 + (lane >> 4) * 8];
        #pragma unroll
        for (int n = 0; n < 4; ++n)
            b[n] = *(const short8*)&Bs[(wc + n * 16 + (lane & 15)) * 32 + (lane >> 4) * 8];
        #pragma unroll
        for (int m = 0; m < 4; ++m)
            #pragma unroll
            for (int n = 0; n < 4; ++n)
                acc[m][n] = __builtin_amdgcn_mfma_f32_16x16x32_bf16(a[m], b[n], acc[m][n], 0, 0, 0);
        if (more) {
            int c = (t + 1) * 32 + (lane & 3) * 8;
            ushort* Ln = lds + (cur ^ 1) * 8192;
            *(uint4*)(Ln + wave * 512 + lane * 8) = bn_relu_pack_l(w0n, sc_l, sh_l, c);
            *(uint4*)(Ln + 2048 + wave * 512 + lane * 8) = bn_relu_pack_l(w1n, sc_l, sh_l, c);
            __builtin_amdgcn_s_barrier();
        }
    }
#undef STAGE_B

    #pragma unroll
    for (int n = 0; n < 4; ++n) {
        int col = col0 + wc + n * 16 + (lane & 15);
        float bb = bias[col];
        #pragma unroll
        for (int m = 0; m < 4; ++m) {
            int rb = row0 + wr + m * 16 + (lane >> 4) * 4;
            #pragma unroll
            for (int r = 0; r < 4; ++r) {
                int row = rb + r;
                if (row < M)
                    Cb[(size_t)row * ldc + col] = f2b(fmaxf(acc[m][n][r] + bb, 0.f));
            }
        }
    }
}

__global__ void mm_bn_fin(const float* __restrict__ sums, const float* __restrict__ gamma,
                          const float* __restrict__ beta,
                          float* __restrict__ scale, float* __restrict__ shift)
{
    int c = blockIdx.x * 256 + threadIdx.x;
    if (c >= 768) return;
    float inv = 1.f / (float)NN;
    float mu = sums[c] * inv;
    float ex2 = sums[768 + c] * inv;
    float var = fmaxf(ex2 - mu * mu, 0.f);
    float rs = rsqrtf(var + 1e-5f);
    float sc = gamma[c] * rs;
    scale[c] = sc;
    shift[c] = beta[c] - mu * sc;
}

// ---------------- out = h2 @ W2 + b2 (h2 bf16 [NN,256], W2 fp32 [256,40]) ----------------
__global__ __launch_bounds__(256) void mm_head2(const ushort* __restrict__ h2b, const float* __restrict__ W2,
                                                const float* __restrict__ b2, float* __restrict__ out)
{
    __shared__ float Ws[256 * 40];
    for (int i = threadIdx.x; i < 256 * 40; i += 256) Ws[i] = W2[i];
    __syncthreads();
    int row = blockIdx.x * 32 + (threadIdx.x >> 3);
    int cg = (threadIdx.x & 7) * 5;
    if (row >= NN) return;
    const ushort* hr = h2b + (size_t)row * 256;
    float acc[5] = {0, 0, 0, 0, 0};
    for (int k = 0; k < 256; k += 8) {
        uint4 w = *(const uint4*)(hr + k);
        float a0 = b2f_lo(w.x), a1 = b2f_hi(w.x), a2 = b2f_lo(w.y), a3 = b2f_hi(w.y);
        float a4 = b2f_lo(w.z), a5 = b2f_hi(w.z), a6 = b2f_lo(w.w), a7 = b2f_hi(w.w);
        #pragma unroll
        for (int j = 0; j < 5; ++j) {
            acc[j] += a0 * Ws[(k + 0) * 40 + cg + j] + a1 * Ws[(k + 1) * 40 + cg + j]
                    + a2 * Ws[(k + 2) * 40 + cg + j] + a3 * Ws[(k + 3) * 40 + cg + j]
                    + a4 * Ws[(k + 4) * 40 + cg + j] + a5 * Ws[(k + 5) * 40 + cg + j]
                    + a6 * Ws[(k + 6) * 40 + cg + j] + a7 * Ws[(k + 7) * 40 + cg + j];
        }
    }
    #pragma unroll
    for (int j = 0; j < 5; ++j) out[(size_t)row * 40 + cg + j] = acc[j] + b2[cg + j];
}

extern "C" void kernel_launch(void* const* d_in, const int* in_sizes, int n_in,
                              void* d_out, int out_size, void* d_ws, size_t ws_size,
                              hipStream_t stream)
{
    const float* x      = (const float*)d_in[0];
    const int*   ei     = (const int*)d_in[1];
    const float* W_gat  = (const float*)d_in[2];
    const float* att_s  = (const float*)d_in[3];
    const float* att_d  = (const float*)d_in[4];
    const float* b_gat  = (const float*)d_in[5];
    const float* W_gin1 = (const float*)d_in[6];
    const float* b_gin1 = (const float*)d_in[7];
    const float* W_gin2 = (const float*)d_in[8];
    const float* b_gin2 = (const float*)d_in[9];
    const float* W_gcn  = (const float*)d_in[10];
    const float* b_gcn  = (const float*)d_in[11];
    const float* gamma  = (const float*)d_in[12];
    const float* beta   = (const float*)d_in[13];
    const float* W_lin  = (const float*)d_in[14];
    const float* b_lin  = (const float*)d_in[15];
    const float* W_lin2 = (const float*)d_in[16];
    const float* b_lin2 = (const float*)d_in[17];
    const int* src = ei;
    const int* dst = ei + NE;
    float* out = (float*)d_out;

    float* ws = (float*)d_ws;
    size_t off = 0;
    ushort* xb      = (ushort*)(ws + off); off += (size_t)NN * 64;    // [NN][128] bf16
    ushort* aggb    = (ushort*)(ws + off); off += (size_t)NN * 192;   // [NN][384] bf16: gat|gin|gcn
    ushort* hid_b   = (ushort*)(ws + off); off += (size_t)NN * 128;   // GIN hidden; later h2
    ushort* xcb     = (ushort*)(ws + off); off += (size_t)NN * 384;   // [NN][768] bf16
    float* es       = ws + off; off += NN;
    float* ed       = ws + off; off += NN;
    float* dis      = ws + off; off += NN;
    float* va       = ws + off; off += 128;
    float* vd       = ws + off; off += 128;
    float* bnsum    = ws + off; off += 1536;
    float* bscale   = ws + off; off += 768;
    float* bshift   = ws + off; off += 768;
    ushort* wt_gat  = (ushort*)(ws + off); off += 128 * 256 / 2;
    ushort* wt_gin1 = (ushort*)(ws + off); off += 128 * 256 / 2;
    ushort* wt_gin2 = (ushort*)(ws + off); off += 256 * 256 / 2;
    ushort* wt_gcn  = (ushort*)(ws + off); off += 128 * 256 / 2;
    ushort* wt_lin  = (ushort*)(ws + off); off += 768 * 256 / 2;
    int* part       = (int*)(ws + off); off += 256;
    int* row_ptr    = (int*)(ws + off); off += NN + 1;
    int* cursor     = (int*)(ws + off); off += NN;
    int* csr_src    = (int*)(ws + off); off += NE;

    dim3 blk(256);
    dim3 gemm_grid((NN + 127) / 128, 2);       // N=256 -> 2 col blocks
    dim3 gemm_grid3((NN + 127) / 128, 2, 3);   // 3 branch GEMMs batched
    const int NB = (NN + 255) / 256;           // scan tiles

    // ---- zero accumulators early ----
    hipMemsetAsync(bnsum, 0, 1536 * sizeof(float), stream);
    hipMemsetAsync(cursor, 0, NN * sizeof(int), stream);

    // ---- weight transposes / attention vectors ----
    mm_wt<<<(128 * 256 + 255) / 256, blk, 0, stream>>>(W_gat, wt_gat, 128, 256);
    mm_wt<<<(128 * 256 + 255) / 256, blk, 0, stream>>>(W_gin1, wt_gin1, 128, 256);
    mm_wt<<<(256 * 256 + 255) / 256, blk, 0, stream>>>(W_gin2, wt_gin2, 256, 256);
    mm_wt<<<(128 * 256 + 255) / 256, blk, 0, stream>>>(W_gcn, wt_gcn, 128, 256);
    mm_wt<<<(768 * 256 + 255) / 256, blk, 0, stream>>>(W_lin, wt_lin, 768, 256);
    mm_attvec<<<1, blk, 0, stream>>>(W_gat, att_s, att_d, va, vd);

    // ---- fused convert + attention dots ----
    mm_cvt_es<<<(NN + 3) / 4, blk, 0, stream>>>(x, va, vd, xb, es, ed);

    // ---- CSR build ----
    mm_count<<<(NE + 255) / 256, blk, 0, stream>>>(dst, cursor);
    mm_scan1<<<NB, blk, 0, stream>>>(cursor, part);
    mm_scan2<<<1, blk, 0, stream>>>(part, NB);
    mm_scan3<<<NB, blk, 0, stream>>>(cursor, part, row_ptr, cursor);
    mm_dis<<<(NN + 255) / 256, blk, 0, stream>>>(row_ptr, dis);
    mm_fill<<<(NE + 255) / 256, blk, 0, stream>>>(src, dst, cursor, csr_src);

    // ---- fused per-node softmax + 3-way gather ----
    mm_node_agg<<<(NN + 3) / 4, blk, 0, stream>>>(row_ptr, csr_src, es, ed, dis, xb, aggb);

    // ---- branch GEMMs (z-batched; BN stats fused in epilogue) ----
    mm_gemm3<<<gemm_grid3, blk, 0, stream>>>(aggb, wt_gat, wt_gin1, wt_gcn,
                                             b_gat, b_gin1, b_gcn, bnsum, xcb, hid_b);
    // ---- gin2 (depends on gin1 output) ----
    mm_gemm_bf<<<gemm_grid, blk, 0, stream>>>(hid_b, 256, wt_gin2, b_gin2, bnsum + 256,
                                              xcb + 256, 768, NN, 256, 0);

    // ---- BN scale/shift ----
    mm_bn_fin<<<3, blk, 0, stream>>>(bnsum, gamma, beta, bscale, bshift);

    // ---- head: BN+ReLU fused into A staging (pipelined) ----
    mm_gemm_bn<<<gemm_grid, blk, 0, stream>>>(xcb, wt_lin, b_lin, bscale, bshift, hid_b, 256, NN);
    mm_head2<<<(NN + 31) / 32, blk, 0, stream>>>(hid_b, W_lin2, b_lin2, out);
}